// Round 1
// baseline (507.989 us; speedup 1.0000x reference)
//
#include <hip/hip_runtime.h>
#include <math.h>

#define NQ 16
#define NBATCH 512
#define NCLS 100

__device__ __forceinline__ float2 cmulc(float2 a, float2 b){
  return make_float2(a.x*b.x - a.y*b.y, a.x*b.y + a.y*b.x);
}
__device__ __forceinline__ float2 caddc(float2 a, float2 b){
  return make_float2(a.x+b.x, a.y+b.y);
}
__device__ __forceinline__ float2 shflx2(float2 a, int m){
  return make_float2(__shfl_xor(a.x, m, 64), __shfl_xor(a.y, m, 64));
}

// generic 1q gate on a register-mapped qubit (mask M within r index 0..15)
template<int M>
__device__ __forceinline__ void reg_gate(float2 (&v)[16], float2 u00, float2 u01, float2 u10, float2 u11){
  #pragma unroll
  for (int r=0;r<16;r++) if (!(r&M)){
    float2 a = v[r], b = v[r|M];
    v[r]   = caddc(cmulc(u00,a), cmulc(u01,b));
    v[r|M] = caddc(cmulc(u10,a), cmulc(u11,b));
  }
}
// generic 1q gate on a lane-mapped qubit (lane mask LM)
template<int LM>
__device__ __forceinline__ void lane_gate(float2 (&v)[16], int lane, float2 u00, float2 u01, float2 u10, float2 u11){
  bool hi = (lane & LM) != 0;
  float2 cv = hi ? u11 : u00;   // coefficient on own amplitude
  float2 cp = hi ? u10 : u01;   // coefficient on partner amplitude
  #pragma unroll
  for (int r=0;r<16;r++){
    float2 p = shflx2(v[r], LM);
    v[r] = caddc(cmulc(cv, v[r]), cmulc(cp, p));
  }
}
// CRX: ctrl lane bit LC, tgt lane bit LT.  RX = [[c,-is],[-is,c]] (symmetric)
template<int LC,int LT>
__device__ __forceinline__ void crx_ll(float2 (&v)[16], int lane, float c, float s){
  bool on = (lane & LC) != 0;
  #pragma unroll
  for (int r=0;r<16;r++){
    float2 p = shflx2(v[r], LT);
    float2 nv = make_float2(c*v[r].x + s*p.y, c*v[r].y - s*p.x);
    v[r] = on ? nv : v[r];
  }
}
// CRX: ctrl and tgt both register bits
template<int MC,int MT>
__device__ __forceinline__ void crx_rr(float2 (&v)[16], float c, float s){
  #pragma unroll
  for (int r=0;r<16;r++) if ((r&MC) && !(r&MT)){
    float2 a = v[r], b = v[r|MT];
    v[r]    = make_float2(c*a.x + s*b.y, c*a.y - s*b.x);
    v[r|MT] = make_float2(s*a.y + c*b.x, -s*a.x + c*b.y);
  }
}
// CRX: ctrl lane bit LC, tgt register bit MT
template<int LC,int MT>
__device__ __forceinline__ void crx_lr(float2 (&v)[16], int lane, float c, float s){
  bool on = (lane & LC) != 0;
  #pragma unroll
  for (int r=0;r<16;r++) if (!(r&MT)){
    float2 a = v[r], b = v[r|MT];
    float2 na = make_float2(c*a.x + s*b.y, c*a.y - s*b.x);
    float2 nb = make_float2(s*a.y + c*b.x, -s*a.x + c*b.y);
    v[r]    = on ? na : a;
    v[r|MT] = on ? nb : b;
  }
}
// CRX: ctrl register bit MC, tgt lane bit LT
template<int MC,int LT>
__device__ __forceinline__ void crx_rl(float2 (&v)[16], float c, float s){
  #pragma unroll
  for (int r=0;r<16;r++) if (r&MC){
    float2 p = shflx2(v[r], LT);
    v[r] = make_float2(c*v[r].x + s*p.y, c*v[r].y - s*p.x);
  }
}

// Precompute fused U_i^b = Rot_i * RX(x[b,i]) for both layers, + CRX (c,s) pairs
__global__ __launch_bounds__(256) void kprep(const float* __restrict__ x,
      const float* __restrict__ rot1, const float* __restrict__ crx1,
      const float* __restrict__ rot2, const float* __restrict__ crx2,
      float2* __restrict__ fU, float2* __restrict__ cm)
{
  int t = blockIdx.x*blockDim.x + threadIdx.x;
  if (t < 2*NBATCH*NQ){
    int w  = t & 15;
    int bb = (t>>4) & (NBATCH-1);
    int L  = t >> 13;
    const float* rot = L ? rot2 : rot1;
    float phi = rot[w*3+0], th = rot[w*3+1], om = rot[w*3+2];
    float ct = cosf(0.5f*th), stt = sinf(0.5f*th);
    float a1 = 0.5f*(phi+om), a2 = 0.5f*(phi-om);
    float2 em  = make_float2(cosf(a1), -sinf(a1));
    float2 ep  = make_float2(cosf(a1),  sinf(a1));
    float2 edm = make_float2(cosf(a2), -sinf(a2));
    float2 edp = make_float2(cosf(a2),  sinf(a2));
    float2 R00 = make_float2(em.x*ct,  em.y*ct);
    float2 R01 = make_float2(-edp.x*stt, -edp.y*stt);
    float2 R10 = make_float2(edm.x*stt, edm.y*stt);
    float2 R11 = make_float2(ep.x*ct,  ep.y*ct);
    float xv = x[bb*NQ + w];
    float cx = cosf(0.5f*xv), sx = sinf(0.5f*xv);
    // U = R * RX(x):  RX = [[cx, -i sx],[-i sx, cx]]
    float2 U00 = make_float2(R00.x*cx + R01.y*sx,  R00.y*cx - R01.x*sx);
    float2 U01 = make_float2(R00.y*sx + R01.x*cx, -R00.x*sx + R01.y*cx);
    float2 U10 = make_float2(R10.x*cx + R11.y*sx,  R10.y*cx - R11.x*sx);
    float2 U11 = make_float2(R10.y*sx + R11.x*cx, -R10.x*sx + R11.y*cx);
    float2* o = fU + (size_t)t*4;
    o[0]=U00; o[1]=U01; o[2]=U10; o[3]=U11;
  }
  if (t < 2*NQ){
    int L = t>>4, w = t&15;
    const float* cxl = L ? crx2 : crx1;
    float thc = cxl[w];
    cm[t] = make_float2(cosf(0.5f*thc), sinf(0.5f*thc));
  }
}

// Pass A: local wires 0..9.  lane bits 0..5 = wires 0..5, reg bits 0..3 = wires 6..9.
// Applies U_0..U_9, then CRX(0,1)..CRX(8,9).
// INIT: layer-1 start from |0..0> analytically -> only h==0 tile nonzero -> 1 wave/sample.
template<bool INIT>
__global__ __launch_bounds__(256) void kpassA(float2* __restrict__ st,
      const float2* __restrict__ fU, const float2* __restrict__ cmat,
      int b0, int nsamp)
{
  int lane = threadIdx.x & 63;
  int wv = (blockIdx.x<<2) | (threadIdx.x>>6);
  int bl, h;
  if (INIT){ bl = wv; h = 0; }
  else     { bl = wv>>6; h = wv&63; }
  if (bl >= nsamp) return;
  int bg = b0 + bl;
  float2 v[16];
  size_t base = ((size_t)bl<<16) | ((size_t)h<<10) | (size_t)lane;
  if (INIT){
    #pragma unroll
    for (int r=0;r<16;r++) v[r] = make_float2(0.f,0.f);
    if (lane==0) v[0] = make_float2(1.f,0.f);
  } else {
    #pragma unroll
    for (int r=0;r<16;r++) v[r] = st[base | (size_t)(r<<6)];
  }
  const float2* U = fU + ((size_t)bg<<6);
  lane_gate<1 >(v, lane, U[0], U[1], U[2], U[3]);    // U0
  lane_gate<2 >(v, lane, U[4], U[5], U[6], U[7]);    // U1
  lane_gate<4 >(v, lane, U[8], U[9], U[10],U[11]);   // U2
  lane_gate<8 >(v, lane, U[12],U[13],U[14],U[15]);   // U3
  lane_gate<16>(v, lane, U[16],U[17],U[18],U[19]);   // U4
  lane_gate<32>(v, lane, U[20],U[21],U[22],U[23]);   // U5
  reg_gate<1>(v, U[24],U[25],U[26],U[27]);           // U6
  reg_gate<2>(v, U[28],U[29],U[30],U[31]);           // U7
  reg_gate<4>(v, U[32],U[33],U[34],U[35]);           // U8
  reg_gate<8>(v, U[36],U[37],U[38],U[39]);           // U9
  crx_ll<1,2 >(v, lane, cmat[0].x, cmat[0].y);       // CRX(0,1)
  crx_ll<2,4 >(v, lane, cmat[1].x, cmat[1].y);       // CRX(1,2)
  crx_ll<4,8 >(v, lane, cmat[2].x, cmat[2].y);       // CRX(2,3)
  crx_ll<8,16>(v, lane, cmat[3].x, cmat[3].y);       // CRX(3,4)
  crx_ll<16,32>(v, lane, cmat[4].x, cmat[4].y);      // CRX(4,5)
  crx_lr<32,1>(v, lane, cmat[5].x, cmat[5].y);       // CRX(5,6)
  crx_rr<1,2>(v, cmat[6].x, cmat[6].y);              // CRX(6,7)
  crx_rr<2,4>(v, cmat[7].x, cmat[7].y);              // CRX(7,8)
  crx_rr<4,8>(v, cmat[8].x, cmat[8].y);              // CRX(8,9)
  #pragma unroll
  for (int r=0;r<16;r++) st[base | (size_t)(r<<6)] = v[r];
}

// Pass B: local wires {0,1,2, 9..15}.
// lane bits: b0..b2 = wires 0..2 (addr bits 0..2), b3..b5 = wires 9..11 (addr bits 9..11)
// reg bits:  b0..b3 = wires 12..15 (addr bits 12..15);   h = wires 3..8 (addr bits 3..8)
// Applies U_10..U_15, then CRX(9,10)..CRX(15,0).
template<bool SPARSEIN, bool EXPV>
__global__ __launch_bounds__(256) void kpassB(float2* __restrict__ st,
      const float2* __restrict__ fU, const float2* __restrict__ cmat,
      int b0, int nsamp, float* __restrict__ expv)
{
  int lane = threadIdx.x & 63;
  int wv = (blockIdx.x<<2) | (threadIdx.x>>6);
  int bl = wv>>6, h = wv&63;
  if (bl >= nsamp) return;
  int bg = b0 + bl;
  size_t base = ((size_t)bl<<16) | (size_t)(h<<3) | (size_t)(lane&7) | ((size_t)(lane>>3)<<9);
  float2 v[16];
  if (SPARSEIN){
    // after layer-1 pass A only wires10..15==0 block is nonzero:
    // r==0 and lane<16 (wire10=wire11=0)
    #pragma unroll
    for (int r=0;r<16;r++) v[r] = make_float2(0.f,0.f);
    if (lane < 16) v[0] = st[base];
  } else {
    #pragma unroll
    for (int r=0;r<16;r++) v[r] = st[base | ((size_t)r<<12)];
  }
  const float2* U = fU + ((size_t)bg<<6) + 40;       // wires 10..15
  lane_gate<16>(v, lane, U[0], U[1], U[2], U[3]);    // U10
  lane_gate<32>(v, lane, U[4], U[5], U[6], U[7]);    // U11
  reg_gate<1>(v, U[8], U[9], U[10],U[11]);           // U12
  reg_gate<2>(v, U[12],U[13],U[14],U[15]);           // U13
  reg_gate<4>(v, U[16],U[17],U[18],U[19]);           // U14
  reg_gate<8>(v, U[20],U[21],U[22],U[23]);           // U15
  crx_ll<8,16>(v, lane, cmat[9].x,  cmat[9].y);      // CRX(9,10)
  crx_ll<16,32>(v, lane, cmat[10].x, cmat[10].y);    // CRX(10,11)
  crx_lr<32,1>(v, lane, cmat[11].x, cmat[11].y);     // CRX(11,12)
  crx_rr<1,2>(v, cmat[12].x, cmat[12].y);            // CRX(12,13)
  crx_rr<2,4>(v, cmat[13].x, cmat[13].y);            // CRX(13,14)
  crx_rr<4,8>(v, cmat[14].x, cmat[14].y);            // CRX(14,15)
  crx_rl<8,1>(v, cmat[15].x, cmat[15].y);            // CRX(15,0)
  if (!EXPV){
    #pragma unroll
    for (int r=0;r<16;r++) st[base | ((size_t)r<<12)] = v[r];
  } else {
    float tot=0.f, S0=0.f, S1=0.f, S2=0.f, S3=0.f;
    #pragma unroll
    for (int r=0;r<16;r++){
      float pr = v[r].x*v[r].x + v[r].y*v[r].y;
      tot += pr;
      if (r&1) S0+=pr;
      if (r&2) S1+=pr;
      if (r&4) S2+=pr;
      if (r&8) S3+=pr;
    }
    float val[16];
    val[0]  = (lane&1) ? -tot: tot;
    val[1]  = (lane&2) ? -tot: tot;
    val[2]  = (lane&4) ? -tot: tot;
    val[3]  = (h&1)  ? -tot: tot;
    val[4]  = (h&2)  ? -tot: tot;
    val[5]  = (h&4)  ? -tot: tot;
    val[6]  = (h&8)  ? -tot: tot;
    val[7]  = (h&16) ? -tot: tot;
    val[8]  = (h&32) ? -tot: tot;
    val[9]  = (lane&8) ? -tot: tot;
    val[10] = (lane&16)? -tot: tot;
    val[11] = (lane&32)? -tot: tot;
    val[12] = tot - 2.f*S0;
    val[13] = tot - 2.f*S1;
    val[14] = tot - 2.f*S2;
    val[15] = tot - 2.f*S3;
    #pragma unroll
    for (int d=1; d<64; d<<=1){
      #pragma unroll
      for (int w=0;w<16;w++) val[w] += __shfl_xor(val[w], d, 64);
    }
    if (lane==0){
      #pragma unroll
      for (int w=0;w<16;w++) atomicAdd(expv + bg*NQ + w, val[w]);
    }
  }
}

__global__ __launch_bounds__(128) void klogits(const float* __restrict__ expv,
      const float* __restrict__ W, const float* __restrict__ bias,
      float* __restrict__ out)
{
  int b = blockIdx.x;
  int tid = threadIdx.x;
  __shared__ float f[NQ];
  __shared__ float lg[NCLS];
  if (tid < NQ) f[tid] = expv[b*NQ + tid];
  __syncthreads();
  if (tid < NCLS){
    float acc = bias[tid];
    #pragma unroll
    for (int i=0;i<NQ;i++) acc += f[i]*W[tid*NQ+i];
    lg[tid] = acc;
  }
  __syncthreads();
  if (tid < NCLS){
    float m = -1e30f;
    for (int i=0;i<NCLS;i++) m = fmaxf(m, lg[i]);
    float sum = 0.f;
    for (int i=0;i<NCLS;i++) sum += expf(lg[i]-m);
    out[b*NCLS+tid] = lg[tid] - m - logf(sum);
  }
}

extern "C" void kernel_launch(void* const* d_in, const int* in_sizes, int n_in,
                              void* d_out, int out_size, void* d_ws, size_t ws_size,
                              hipStream_t stream)
{
  const float* x    = (const float*)d_in[0];
  const float* rot1 = (const float*)d_in[1];
  const float* crx1 = (const float*)d_in[2];
  const float* rot2 = (const float*)d_in[3];
  const float* crx2 = (const float*)d_in[4];
  const float* W    = (const float*)d_in[5];
  const float* bias = (const float*)d_in[6];
  float* out = (float*)d_out;

  char* ws = (char*)d_ws;
  float*  expv = (float*)ws;                       // 32 KB
  float2* fU   = (float2*)(ws + (40<<10));         // 512 KB: [2][512][16][4] complex
  float2* cmm  = (float2*)(ws + (560<<10));        // 256 B:  [2][16] (c,s)
  const size_t stOff = (size_t)(576<<10);
  float2* st   = (float2*)(ws + stOff);

  hipMemsetAsync(expv, 0, NBATCH*NQ*sizeof(float), stream);
  kprep<<<(2*NBATCH*NQ + 255)/256, 256, 0, stream>>>(x, rot1, crx1, rot2, crx2, fU, cmm);

  size_t avail = (ws_size > stOff) ? (ws_size - stOff) : 0;
  int chunk = NBATCH;
  while (chunk > 1 && (size_t)chunk*65536*sizeof(float2) > avail) chunk >>= 1;

  for (int b0 = 0; b0 < NBATCH; b0 += chunk){
    int ns = chunk;
    int blocksA0 = (ns + 3)/4;        // init: 1 wave per sample (h==0 only)
    int blocksF  = ns*16;             // 64 waves per sample
    kpassA<true ><<<blocksA0, 256, 0, stream>>>(st, fU,         cmm,      b0, ns);
    kpassB<true, false><<<blocksF, 256, 0, stream>>>(st, fU,     cmm,      b0, ns, nullptr);
    kpassA<false><<<blocksF, 256, 0, stream>>>(st, fU + 32768,  cmm + 16, b0, ns);
    kpassB<false, true ><<<blocksF, 256, 0, stream>>>(st, fU + 32768, cmm + 16, b0, ns, expv);
  }
  klogits<<<NBATCH, 128, 0, stream>>>(expv, W, bias, out);
}

// Round 2
// 395.232 us; speedup vs baseline: 1.2853x; 1.2853x over previous
//
#include <hip/hip_runtime.h>
#include <math.h>

#define NQ 16
#define NBATCH 512
#define NCLS 100

__device__ __forceinline__ float2 cmulc(float2 a, float2 b){
  return make_float2(a.x*b.x - a.y*b.y, a.x*b.y + a.y*b.x);
}
__device__ __forceinline__ float2 caddc(float2 a, float2 b){
  return make_float2(a.x+b.x, a.y+b.y);
}
__device__ __forceinline__ float2 shflx2(float2 a, int m){
  return make_float2(__shfl_xor(a.x, m, 64), __shfl_xor(a.y, m, 64));
}

// 1q gate on a register-mapped qubit (mask M within r index 0..15)
template<int M>
__device__ __forceinline__ void reg_gate(float2 (&v)[16], float2 u00, float2 u01, float2 u10, float2 u11){
  #pragma unroll
  for (int r=0;r<16;r++) if (!(r&M)){
    float2 a = v[r], b = v[r|M];
    v[r]   = caddc(cmulc(u00,a), cmulc(u01,b));
    v[r|M] = caddc(cmulc(u10,a), cmulc(u11,b));
  }
}
// 1q gate on a lane-mapped qubit (lane mask LM)
template<int LM>
__device__ __forceinline__ void lane_gate(float2 (&v)[16], int lane, float2 u00, float2 u01, float2 u10, float2 u11){
  bool hi = (lane & LM) != 0;
  float2 cv = hi ? u11 : u00;
  float2 cp = hi ? u10 : u01;
  #pragma unroll
  for (int r=0;r<16;r++){
    float2 p = shflx2(v[r], LM);
    v[r] = caddc(cmulc(cv, v[r]), cmulc(cp, p));
  }
}
// CRX with ctrl lane bit LC, tgt lane bit LT.  RX = [[c,-is],[-is,c]]
template<int LC,int LT>
__device__ __forceinline__ void crx_ll(float2 (&v)[16], int lane, float c, float s){
  bool on = (lane & LC) != 0;
  #pragma unroll
  for (int r=0;r<16;r++){
    float2 p = shflx2(v[r], LT);
    float2 nv = make_float2(c*v[r].x + s*p.y, c*v[r].y - s*p.x);
    v[r] = on ? nv : v[r];
  }
}
// CRX ctrl/tgt both register bits
template<int MC,int MT>
__device__ __forceinline__ void crx_rr(float2 (&v)[16], float c, float s){
  #pragma unroll
  for (int r=0;r<16;r++) if ((r&MC) && !(r&MT)){
    float2 a = v[r], b = v[r|MT];
    v[r]    = make_float2(c*a.x + s*b.y, c*a.y - s*b.x);
    v[r|MT] = make_float2(s*a.y + c*b.x, -s*a.x + c*b.y);
  }
}
// CRX ctrl lane bit LC, tgt register bit MT
template<int LC,int MT>
__device__ __forceinline__ void crx_lr(float2 (&v)[16], int lane, float c, float s){
  bool on = (lane & LC) != 0;
  #pragma unroll
  for (int r=0;r<16;r++) if (!(r&MT)){
    float2 a = v[r], b = v[r|MT];
    float2 na = make_float2(c*a.x + s*b.y, c*a.y - s*b.x);
    float2 nb = make_float2(s*a.y + c*b.x, -s*a.x + c*b.y);
    v[r]    = on ? na : a;
    v[r|MT] = on ? nb : b;
  }
}
// CRX ctrl register bit MC, tgt lane bit LT
template<int MC,int LT>
__device__ __forceinline__ void crx_rl(float2 (&v)[16], float c, float s){
  #pragma unroll
  for (int r=0;r<16;r++) if (r&MC){
    float2 p = shflx2(v[r], LT);
    v[r] = make_float2(c*v[r].x + s*p.y, c*v[r].y - s*p.x);
  }
}

__device__ __forceinline__ int lds_phys(int c){ return c ^ (((c>>4)^(c>>8))&15); }

// Precompute fused U_i^b = Rot_i * RX(x[b,i]) for both layers, + CRX (c,s)
__global__ __launch_bounds__(256) void kprep(const float* __restrict__ x,
      const float* __restrict__ rot1, const float* __restrict__ crx1,
      const float* __restrict__ rot2, const float* __restrict__ crx2,
      float2* __restrict__ fU, float2* __restrict__ cm)
{
  int t = blockIdx.x*blockDim.x + threadIdx.x;
  if (t < 2*NBATCH*NQ){
    int w  = t & 15;
    int bb = (t>>4) & (NBATCH-1);
    int L  = t >> 13;
    const float* rot = L ? rot2 : rot1;
    float phi = rot[w*3+0], th = rot[w*3+1], om = rot[w*3+2];
    float ct = cosf(0.5f*th), stt = sinf(0.5f*th);
    float a1 = 0.5f*(phi+om), a2 = 0.5f*(phi-om);
    float2 em  = make_float2(cosf(a1), -sinf(a1));
    float2 ep  = make_float2(cosf(a1),  sinf(a1));
    float2 edm = make_float2(cosf(a2), -sinf(a2));
    float2 edp = make_float2(cosf(a2),  sinf(a2));
    float2 R00 = make_float2(em.x*ct,  em.y*ct);
    float2 R01 = make_float2(-edp.x*stt, -edp.y*stt);
    float2 R10 = make_float2(edm.x*stt, edm.y*stt);
    float2 R11 = make_float2(ep.x*ct,  ep.y*ct);
    float xv = x[bb*NQ + w];
    float cx = cosf(0.5f*xv), sx = sinf(0.5f*xv);
    float2 U00 = make_float2(R00.x*cx + R01.y*sx,  R00.y*cx - R01.x*sx);
    float2 U01 = make_float2(R00.y*sx + R01.x*cx, -R00.x*sx + R01.y*cx);
    float2 U10 = make_float2(R10.x*cx + R11.y*sx,  R10.y*cx - R11.x*sx);
    float2 U11 = make_float2(R10.y*sx + R11.x*cx, -R10.x*sx + R11.y*cx);
    float2* o = fU + (size_t)t*4;
    o[0]=U00; o[1]=U01; o[2]=U10; o[3]=U11;
  }
  if (t < 2*NQ){
    int L = t>>4, w = t&15;
    const float* cxl = L ? crx2 : crx1;
    float thc = cxl[w];
    cm[t] = make_float2(cosf(0.5f*thc), sinf(0.5f*thc));
  }
}

// ---------------------------------------------------------------------------
// PASS 1 (one block per sample): product state over wires 0..11 (V0..V11 analytic),
// then L1 ring CRX(0,1)..(10,11).  Output: compact 4096 amps/sample.
// Stage A map: lane={w0..w5}, r={w6..w9}, wv={w10,w11}
// Stage B map: lane={w11,w0,w1,w2,w9,w10}, r={w3,w4,w5,w6}, wv={w7,w8}
// Compact layout bits: [0]=w11 [1]=w0 [2..5]=w1..w4 [6,7]=w5,w6 [8,9]=w7,w8 [10]=w9 [11]=w10
__global__ __launch_bounds__(256) void kpass1(const float2* __restrict__ fU1,
      const float2* __restrict__ cm1, float2* __restrict__ compact)
{
  int lane = threadIdx.x & 63;
  int wv = threadIdx.x >> 6;
  int bg = blockIdx.x;
  const float2* U = fU1 + ((size_t)bg<<6);
  float2 P = make_float2(1.f,0.f);
  #pragma unroll
  for (int i=0;i<6;i++){
    float2 vi = ((lane>>i)&1) ? U[4*i+2] : U[4*i];
    P = cmulc(P, vi);
  }
  {
    float2 v10 = (wv&1) ? U[42] : U[40];
    float2 v11 = ((wv>>1)&1) ? U[46] : U[44];
    P = cmulc(P, cmulc(v10,v11));
  }
  float2 v[16];
  #pragma unroll
  for (int r=0;r<16;r++){
    float2 q = P;
    #pragma unroll
    for (int k=0;k<4;k++){
      float2 vi = ((r>>k)&1) ? U[4*(6+k)+2] : U[4*(6+k)];
      q = cmulc(q, vi);
    }
    v[r] = q;
  }
  crx_ll<1,2 >(v,lane,cm1[0].x,cm1[0].y);   // CRX(0,1)
  crx_ll<2,4 >(v,lane,cm1[1].x,cm1[1].y);
  crx_ll<4,8 >(v,lane,cm1[2].x,cm1[2].y);
  crx_ll<8,16>(v,lane,cm1[3].x,cm1[3].y);
  crx_ll<16,32>(v,lane,cm1[4].x,cm1[4].y);
  crx_lr<32,1>(v,lane,cm1[5].x,cm1[5].y);   // CRX(5,6)
  crx_rr<1,2>(v,cm1[6].x,cm1[6].y);
  crx_rr<2,4>(v,cm1[7].x,cm1[7].y);
  crx_rr<4,8>(v,cm1[8].x,cm1[8].y);         // CRX(8,9)
  __shared__ float2 lds[4096];
  __syncthreads();
  #pragma unroll
  for (int r=0;r<16;r++){
    int c = lane | (r<<6) | (wv<<10);
    lds[lds_phys(c)] = v[r];
  }
  __syncthreads();
  #pragma unroll
  for (int r=0;r<16;r++){
    int c = ((lane>>1)&7) | (r<<3) | (wv<<7) | (((lane>>4)&3)<<9) | ((lane&1)<<11);
    v[r] = lds[lds_phys(c)];
  }
  crx_ll<16,32>(v,lane,cm1[9].x, cm1[9].y);  // CRX(9,10)
  crx_ll<32,1 >(v,lane,cm1[10].x,cm1[10].y); // CRX(10,11)
  float2* outp = compact + ((size_t)bg<<12);
  #pragma unroll
  for (int r=0;r<16;r++){
    int a = (lane&15) | (r<<4) | (wv<<8) | ((lane>>4)<<10);
    outp[a] = v[r];
  }
}

// ---------------------------------------------------------------------------
// PASS 2 (16 blocks/sample, h = w7..w10): prefactor V12..V15, L1 CRX(11,12)..(15,0),
// L2 W0..W6, L2 CRX(0,1)..(5,6).  Writes full state in L23 layout.
// Stage A: lane={w11,w12,w13,w14,w15,w0}, r={w1..w4}, wv={w5,w6}
// Stage B: lane={w4,w5,w6,w11,w12,w13}, r={w14,w15,w0,w1}, wv={w2,w3}
// Stage C: lane={w11,w12,w13,w14,w15,w6}, r={w2,w3,w4,w5}, wv={w0,w1}
// L23 addr: [0..5]=lane wires, [6,7]=w0,w1, [8..11]=w7..w10, [12..15]=w2..w5
__global__ __launch_bounds__(256) void kpass2(const float2* __restrict__ compact,
      const float2* __restrict__ fU1, const float2* __restrict__ fU2,
      const float2* __restrict__ cm1, const float2* __restrict__ cm2,
      float2* __restrict__ st, int b0, int nsamp)
{
  int lane = threadIdx.x & 63;
  int wv = threadIdx.x >> 6;
  int blk = blockIdx.x;
  int bl = blk >> 4, h = blk & 15;
  int bg = b0 + bl;
  const float2* A  = compact + ((size_t)bg<<12);
  const float2* U1 = fU1 + ((size_t)bg<<6);
  const float2* U2 = fU2 + ((size_t)bg<<6);
  float2 pf = make_float2(1.f,0.f);
  #pragma unroll
  for (int k=0;k<4;k++){
    float2 vi = ((lane>>(1+k))&1) ? U1[4*(12+k)+2] : U1[4*(12+k)];
    pf = cmulc(pf, vi);
  }
  float2 v[16];
  #pragma unroll
  for (int r=0;r<16;r++){
    int a = (lane&1) | (((lane>>5)&1)<<1) | (r<<2) | (wv<<6) | (h<<8);
    v[r] = cmulc(pf, A[a]);
  }
  crx_ll<1,2 >(v,lane,cm1[11].x,cm1[11].y);  // L1 CRX(11,12)
  crx_ll<2,4 >(v,lane,cm1[12].x,cm1[12].y);
  crx_ll<4,8 >(v,lane,cm1[13].x,cm1[13].y);
  crx_ll<8,16>(v,lane,cm1[14].x,cm1[14].y);
  crx_ll<16,32>(v,lane,cm1[15].x,cm1[15].y); // L1 CRX(15,0)
  lane_gate<32>(v,lane,U2[0],U2[1],U2[2],U2[3]);   // W0
  reg_gate<1>(v,U2[4],U2[5],U2[6],U2[7]);          // W1
  reg_gate<2>(v,U2[8],U2[9],U2[10],U2[11]);        // W2
  reg_gate<4>(v,U2[12],U2[13],U2[14],U2[15]);      // W3
  reg_gate<8>(v,U2[16],U2[17],U2[18],U2[19]);      // W4
  crx_lr<32,1>(v,lane,cm2[0].x,cm2[0].y);          // L2 CRX(0,1)
  crx_rr<1,2>(v,cm2[1].x,cm2[1].y);
  crx_rr<2,4>(v,cm2[2].x,cm2[2].y);
  crx_rr<4,8>(v,cm2[3].x,cm2[3].y);                // L2 CRX(3,4)
  __shared__ float2 lds[4096];
  __syncthreads();
  #pragma unroll
  for (int r=0;r<16;r++){
    int c = ((lane>>5)&1) | (r<<1) | (wv<<5) | ((lane&31)<<7);
    lds[lds_phys(c)] = v[r];
  }
  __syncthreads();
  #pragma unroll
  for (int r=0;r<16;r++){
    int c = ((r>>2)&3) | (wv<<2) | ((lane&63)<<4) | ((r&3)<<10);
    v[r] = lds[lds_phys(c)];
  }
  lane_gate<2>(v,lane,U2[20],U2[21],U2[22],U2[23]); // W5
  lane_gate<4>(v,lane,U2[24],U2[25],U2[26],U2[27]); // W6
  crx_ll<1,2>(v,lane,cm2[4].x,cm2[4].y);            // L2 CRX(4,5)
  crx_ll<2,4>(v,lane,cm2[5].x,cm2[5].y);            // L2 CRX(5,6)
  __syncthreads();
  #pragma unroll
  for (int r=0;r<16;r++){
    int c = ((r>>2)&3) | (wv<<2) | ((lane&63)<<4) | ((r&3)<<10);
    lds[lds_phys(c)] = v[r];
  }
  __syncthreads();
  #pragma unroll
  for (int r=0;r<16;r++){
    int c = wv | (r<<2) | (((lane>>5)&1)<<6) | ((lane&31)<<7);
    v[r] = lds[lds_phys(c)];
  }
  float2* S = st + ((size_t)bl<<16);
  #pragma unroll
  for (int r=0;r<16;r++){
    int a = lane | (wv<<6) | (h<<8) | (r<<12);
    S[a] = v[r];
  }
}

// ---------------------------------------------------------------------------
// PASS 3 (16 blocks/sample, h = w2..w5): W7..W15, L2 CRX(6,7)..(15,0), expvals.
// Stage A: lane={w11,w12,w13,w14,w15,w6}, r={w7,w8,w9,w10}, wv={w0,w1}
// Stage B: lane={w15,w0,w6,w7,w8,w9}, r={w10,w11,w12,w13}, wv={w14,w1}
__global__ __launch_bounds__(256) void kpass3(const float2* __restrict__ st,
      const float2* __restrict__ fU2, const float2* __restrict__ cm2,
      float* __restrict__ expv, int b0, int nsamp)
{
  int lane = threadIdx.x & 63;
  int wv = threadIdx.x >> 6;
  int blk = blockIdx.x;
  int bl = blk >> 4, h = blk & 15;
  int bg = b0 + bl;
  const float2* S = st + ((size_t)bl<<16);
  const float2* U2 = fU2 + ((size_t)bg<<6);
  float2 v[16];
  #pragma unroll
  for (int r=0;r<16;r++){
    int a = lane | (wv<<6) | (r<<8) | (h<<12);
    v[r] = S[a];
  }
  lane_gate<1 >(v,lane,U2[44],U2[45],U2[46],U2[47]); // W11
  lane_gate<2 >(v,lane,U2[48],U2[49],U2[50],U2[51]); // W12
  lane_gate<4 >(v,lane,U2[52],U2[53],U2[54],U2[55]); // W13
  lane_gate<8 >(v,lane,U2[56],U2[57],U2[58],U2[59]); // W14
  lane_gate<16>(v,lane,U2[60],U2[61],U2[62],U2[63]); // W15
  reg_gate<1>(v,U2[28],U2[29],U2[30],U2[31]);        // W7
  reg_gate<2>(v,U2[32],U2[33],U2[34],U2[35]);        // W8
  reg_gate<4>(v,U2[36],U2[37],U2[38],U2[39]);        // W9
  reg_gate<8>(v,U2[40],U2[41],U2[42],U2[43]);        // W10
  crx_lr<32,1>(v,lane,cm2[6].x,cm2[6].y);            // CRX(6,7)
  crx_rr<1,2>(v,cm2[7].x,cm2[7].y);
  crx_rr<2,4>(v,cm2[8].x,cm2[8].y);
  crx_rr<4,8>(v,cm2[9].x,cm2[9].y);                  // CRX(9,10)
  crx_rl<8,1>(v,cm2[10].x,cm2[10].y);                // CRX(10,11)
  crx_ll<1,2 >(v,lane,cm2[11].x,cm2[11].y);          // CRX(11,12)
  crx_ll<2,4 >(v,lane,cm2[12].x,cm2[12].y);
  crx_ll<4,8 >(v,lane,cm2[13].x,cm2[13].y);
  crx_ll<8,16>(v,lane,cm2[14].x,cm2[14].y);          // CRX(14,15)
  __shared__ float2 lds[4096];
  __syncthreads();
  #pragma unroll
  for (int r=0;r<16;r++){
    int c = wv | (((lane>>5)&1)<<2) | (r<<3) | ((lane&31)<<7);
    lds[lds_phys(c)] = v[r];
  }
  __syncthreads();
  #pragma unroll
  for (int r=0;r<16;r++){
    int c = ((lane>>1)&1) | (((wv>>1)&1)<<1) | (((lane>>2)&15)<<2) | (r<<6)
          | ((wv&1)<<10) | ((lane&1)<<11);
    v[r] = lds[lds_phys(c)];
  }
  crx_ll<1,2>(v,lane,cm2[15].x,cm2[15].y);           // CRX(15,0)
  // expvals: lane wires {w15,w0,w6,w7,w8,w9}, r wires {w10..w13}, wv {w14,w1}, h {w2..w5}
  float tot=0.f, S0=0.f, S1=0.f, S2=0.f, S3=0.f;
  #pragma unroll
  for (int r=0;r<16;r++){
    float p = v[r].x*v[r].x + v[r].y*v[r].y;
    tot += p;
    if (r&1) S0+=p;
    if (r&2) S1+=p;
    if (r&4) S2+=p;
    if (r&8) S3+=p;
  }
  float s = tot;
  float u[6];
  #pragma unroll
  for (int b=0;b<6;b++){
    int m = 1<<b;
    float t = __shfl_xor(s, m, 64);
    u[b] = s - t;
    s = s + t;
    #pragma unroll
    for (int j=0;j<6;j++) if (j<b) u[j] += __shfl_xor(u[j], m, 64);
  }
  #pragma unroll
  for (int d=1; d<64; d<<=1){
    S0 += __shfl_xor(S0, d, 64);
    S1 += __shfl_xor(S1, d, 64);
    S2 += __shfl_xor(S2, d, 64);
    S3 += __shfl_xor(S3, d, 64);
  }
  __shared__ float ef[4][16];
  if (lane==0){
    ef[wv][15]=u[0]; ef[wv][0]=u[1]; ef[wv][6]=u[2];
    ef[wv][7]=u[3];  ef[wv][8]=u[4]; ef[wv][9]=u[5];
    ef[wv][10]=s-2.f*S0; ef[wv][11]=s-2.f*S1; ef[wv][12]=s-2.f*S2; ef[wv][13]=s-2.f*S3;
    ef[wv][14]=(wv&1)?-s:s; ef[wv][1]=(wv&2)?-s:s;
    ef[wv][2]=(h&1)?-s:s; ef[wv][3]=(h&2)?-s:s; ef[wv][4]=(h&4)?-s:s; ef[wv][5]=(h&8)?-s:s;
  }
  __syncthreads();
  if (threadIdx.x < 16){
    float r4 = ef[0][threadIdx.x]+ef[1][threadIdx.x]+ef[2][threadIdx.x]+ef[3][threadIdx.x];
    atomicAdd(expv + (size_t)bg*NQ + threadIdx.x, r4);
  }
}

__global__ __launch_bounds__(128) void klogits(const float* __restrict__ expv,
      const float* __restrict__ W, const float* __restrict__ bias,
      float* __restrict__ out)
{
  int b = blockIdx.x;
  int tid = threadIdx.x;
  __shared__ float f[NQ];
  __shared__ float lg[NCLS];
  if (tid < NQ) f[tid] = expv[b*NQ + tid];
  __syncthreads();
  if (tid < NCLS){
    float acc = bias[tid];
    #pragma unroll
    for (int i=0;i<NQ;i++) acc += f[i]*W[tid*NQ+i];
    lg[tid] = acc;
  }
  __syncthreads();
  if (tid < NCLS){
    float m = -1e30f;
    for (int i=0;i<NCLS;i++) m = fmaxf(m, lg[i]);
    float sum = 0.f;
    for (int i=0;i<NCLS;i++) sum += expf(lg[i]-m);
    out[b*NCLS+tid] = lg[tid] - m - logf(sum);
  }
}

extern "C" void kernel_launch(void* const* d_in, const int* in_sizes, int n_in,
                              void* d_out, int out_size, void* d_ws, size_t ws_size,
                              hipStream_t stream)
{
  const float* x    = (const float*)d_in[0];
  const float* rot1 = (const float*)d_in[1];
  const float* crx1 = (const float*)d_in[2];
  const float* rot2 = (const float*)d_in[3];
  const float* crx2 = (const float*)d_in[4];
  const float* W    = (const float*)d_in[5];
  const float* bias = (const float*)d_in[6];
  float* out = (float*)d_out;

  char* ws = (char*)d_ws;
  float*  expv = (float*)ws;                          // 32 KB
  float2* fU   = (float2*)(ws + (40<<10));            // 512 KB
  float2* cmm  = (float2*)(ws + (560<<10));           // 256 B
  float2* compact = (float2*)(ws + (576<<10));        // 16 MB
  const size_t stOff = (size_t)(576<<10) + ((size_t)NBATCH<<15);
  float2* st   = (float2*)(ws + stOff);

  hipMemsetAsync(expv, 0, NBATCH*NQ*sizeof(float), stream);
  kprep<<<(2*NBATCH*NQ + 255)/256, 256, 0, stream>>>(x, rot1, crx1, rot2, crx2, fU, cmm);

  float2* fU1 = fU;
  float2* fU2 = fU + 32768;
  float2* cm1 = cmm;
  float2* cm2 = cmm + 16;

  kpass1<<<NBATCH, 256, 0, stream>>>(fU1, cm1, compact);

  size_t avail = (ws_size > stOff) ? (ws_size - stOff) : 0;
  int chunk = NBATCH;
  while (chunk > 1 && (size_t)chunk*65536*sizeof(float2) > avail) chunk >>= 1;

  for (int b0 = 0; b0 < NBATCH; b0 += chunk){
    int ns = chunk;
    kpass2<<<ns*16, 256, 0, stream>>>(compact, fU1, fU2, cm1, cm2, st, b0, ns);
    kpass3<<<ns*16, 256, 0, stream>>>(st, fU2, cm2, expv, b0, ns);
  }
  klogits<<<NBATCH, 128, 0, stream>>>(expv, W, bias, out);
}

// Round 3
// 283.608 us; speedup vs baseline: 1.7912x; 1.3936x over previous
//
#include <hip/hip_runtime.h>
#include <math.h>

#define NQ 16
#define NBATCH 512
#define NCLS 100

__device__ __forceinline__ float2 cmulc(float2 a, float2 b){
  return make_float2(a.x*b.x - a.y*b.y, a.x*b.y + a.y*b.x);
}
__device__ __forceinline__ float2 caddc(float2 a, float2 b){
  return make_float2(a.x+b.x, a.y+b.y);
}
// RX pair update: (a,b) -> (c*a - i*s*b, -i*s*a + c*b)
__device__ __forceinline__ void rx_pair(float2 &a, float2 &b, float c, float s){
  float2 na = make_float2(c*a.x + s*b.y, c*a.y - s*b.x);
  float2 nb = make_float2(s*a.y + c*b.x, -s*a.x + c*b.y);
  a = na; b = nb;
}
// CRX, per-lane predicate ctrl (folds predicate into coefficients: off -> identity, exact)
template<int MT>
__device__ __forceinline__ void crx_pred(float2 (&v)[16], bool on, float c, float s){
  float cc = on ? c : 1.0f;
  float ss = on ? s : 0.0f;
  #pragma unroll
  for (int r=0;r<16;r++) if(!(r&MT)) rx_pair(v[r], v[r|MT], cc, ss);
}
// CRX applied unconditionally (call under uniform branch)
template<int MT>
__device__ __forceinline__ void crx_on(float2 (&v)[16], float c, float s){
  #pragma unroll
  for (int r=0;r<16;r++) if(!(r&MT)) rx_pair(v[r], v[r|MT], c, s);
}
// CRX ctrl and tgt both register bits
template<int MC,int MT>
__device__ __forceinline__ void crx_rr(float2 (&v)[16], float c, float s){
  #pragma unroll
  for (int r=0;r<16;r++) if((r&MC)&&!(r&MT)) rx_pair(v[r], v[r|MT], c, s);
}
// full 1q gate on register bit M
template<int M>
__device__ __forceinline__ void reg_gate(float2 (&v)[16], float2 u00, float2 u01, float2 u10, float2 u11){
  #pragma unroll
  for (int r=0;r<16;r++) if(!(r&M)){
    float2 a = v[r], b = v[r|M];
    v[r]   = caddc(cmulc(u00,a), cmulc(u01,b));
    v[r|M] = caddc(cmulc(u10,a), cmulc(u11,b));
  }
}

__device__ __forceinline__ int lds_phys(int c){ return c ^ (((c>>4)^(c>>8))&15); }

// Precompute fused U_i^b = Rot_i * RX(x[b,i]) for both layers, + CRX (c,s)
__global__ __launch_bounds__(256) void kprep(const float* __restrict__ x,
      const float* __restrict__ rot1, const float* __restrict__ crx1,
      const float* __restrict__ rot2, const float* __restrict__ crx2,
      float2* __restrict__ fU, float2* __restrict__ cm)
{
  int t = blockIdx.x*blockDim.x + threadIdx.x;
  if (t < 2*NBATCH*NQ){
    int w  = t & 15;
    int bb = (t>>4) & (NBATCH-1);
    int L  = t >> 13;
    const float* rot = L ? rot2 : rot1;
    float phi = rot[w*3+0], th = rot[w*3+1], om = rot[w*3+2];
    float ct = cosf(0.5f*th), stt = sinf(0.5f*th);
    float a1 = 0.5f*(phi+om), a2 = 0.5f*(phi-om);
    float2 em  = make_float2(cosf(a1), -sinf(a1));
    float2 ep  = make_float2(cosf(a1),  sinf(a1));
    float2 edm = make_float2(cosf(a2), -sinf(a2));
    float2 edp = make_float2(cosf(a2),  sinf(a2));
    float2 R00 = make_float2(em.x*ct,  em.y*ct);
    float2 R01 = make_float2(-edp.x*stt, -edp.y*stt);
    float2 R10 = make_float2(edm.x*stt, edm.y*stt);
    float2 R11 = make_float2(ep.x*ct,  ep.y*ct);
    float xv = x[bb*NQ + w];
    float cx = cosf(0.5f*xv), sx = sinf(0.5f*xv);
    float2 U00 = make_float2(R00.x*cx + R01.y*sx,  R00.y*cx - R01.x*sx);
    float2 U01 = make_float2(R00.y*sx + R01.x*cx, -R00.x*sx + R01.y*cx);
    float2 U10 = make_float2(R10.x*cx + R11.y*sx,  R10.y*cx - R11.x*sx);
    float2 U11 = make_float2(R10.y*sx + R11.x*cx, -R10.x*sx + R11.y*cx);
    float2* o = fU + (size_t)t*4;
    o[0]=U00; o[1]=U01; o[2]=U10; o[3]=U11;
  }
  if (t < 2*NQ){
    int L = t>>4, w = t&15;
    const float* cxl = L ? crx2 : crx1;
    float thc = cxl[w];
    cm[t] = make_float2(cosf(0.5f*thc), sinf(0.5f*thc));
  }
}

// ---------------------------------------------------------------------------
// PASS 1: one block/sample. Product state wires 0..11 + L1 CRX(0,1)..(10,11).
// Canonical c bits = wires 0..11.
// Stage A: r={1,2,3,4} lane={0,5,6,7,8,9} wv={10,11}
// Stage B: r={5,6,7,8} lane={4,0,1,2,3,9} wv={10,11}
// Stage C: r={9,10,11,8} lane={0,1,2,3,4,5} wv={6,7}
// Stage D: r={7,8,9,10} lane={11,0,1,2,3,4} wv={5,6}  (write layout)
// compact addr bits: [0..5]={11,0,1,2,3,4} [6,7]={5,6} [8..11]={7,8,9,10}
__global__ __launch_bounds__(256) void kpass1(const float2* __restrict__ fU1,
      const float2* __restrict__ cm1, float2* __restrict__ compact)
{
  int lane = threadIdx.x & 63;
  int wv = threadIdx.x >> 6;
  int bg = blockIdx.x;
  const float2* U = fU1 + ((size_t)bg<<6);
  // product amplitude over lane/wv wires {0,5,6,7,8,9,10,11}
  float2 a = (lane&1) ? U[2] : U[0];                       // V0
  a = cmulc(a, ((lane>>1)&1) ? U[22] : U[20]);             // V5
  a = cmulc(a, ((lane>>2)&1) ? U[26] : U[24]);             // V6
  a = cmulc(a, ((lane>>3)&1) ? U[30] : U[28]);             // V7
  a = cmulc(a, ((lane>>4)&1) ? U[34] : U[32]);             // V8
  a = cmulc(a, ((lane>>5)&1) ? U[38] : U[36]);             // V9
  a = cmulc(a, (wv&1) ? U[42] : U[40]);                    // V10
  a = cmulc(a, ((wv>>1)&1) ? U[46] : U[44]);               // V11
  // progressive: v[r] = a * V1[r0]*V2[r1]*V3[r2]*V4[r3]
  float2 v[16];
  v[0] = cmulc(a, U[4]);  v[1] = cmulc(a, U[6]);           // V1 cols
  v[2] = cmulc(v[0], U[10]); v[3] = cmulc(v[1], U[10]);    // V2 col1
  v[0] = cmulc(v[0], U[8]);  v[1] = cmulc(v[1], U[8]);
  #pragma unroll
  for (int i=0;i<4;i++){ v[i+4]=cmulc(v[i],U[14]); v[i]=cmulc(v[i],U[12]); }  // V3
  #pragma unroll
  for (int i=0;i<8;i++){ v[i+8]=cmulc(v[i],U[18]); v[i]=cmulc(v[i],U[16]); }  // V4
  // Stage A gates
  crx_pred<1>(v, (lane&1)!=0, cm1[0].x, cm1[0].y);  // CRX(0,1)
  crx_rr<1,2>(v, cm1[1].x, cm1[1].y);               // CRX(1,2)
  crx_rr<2,4>(v, cm1[2].x, cm1[2].y);               // CRX(2,3)
  crx_rr<4,8>(v, cm1[3].x, cm1[3].y);               // CRX(3,4)
  __shared__ float2 lds[4096];
  // T1: A -> B
  #pragma unroll
  for (int r=0;r<16;r++){
    int c = (lane&1) | (r<<1) | (((lane>>1)&31)<<5) | (wv<<10);
    lds[lds_phys(c)] = v[r];
  }
  __syncthreads();
  #pragma unroll
  for (int r=0;r<16;r++){
    int c = ((lane>>1)&15) | ((lane&1)<<4) | (r<<5) | (((lane>>5)&1)<<9) | (wv<<10);
    v[r] = lds[lds_phys(c)];
  }
  crx_pred<1>(v, (lane&1)!=0, cm1[4].x, cm1[4].y);  // CRX(4,5)
  crx_rr<1,2>(v, cm1[5].x, cm1[5].y);               // CRX(5,6)
  crx_rr<2,4>(v, cm1[6].x, cm1[6].y);               // CRX(6,7)
  crx_rr<4,8>(v, cm1[7].x, cm1[7].y);               // CRX(7,8)
  __syncthreads();
  // T2: B -> C
  #pragma unroll
  for (int r=0;r<16;r++){
    int c = ((lane>>1)&15) | ((lane&1)<<4) | (r<<5) | (((lane>>5)&1)<<9) | (wv<<10);
    lds[lds_phys(c)] = v[r];
  }
  __syncthreads();
  #pragma unroll
  for (int r=0;r<16;r++){
    int c = (lane&63) | (wv<<6) | (((r>>3)&1)<<8) | ((r&7)<<9);
    v[r] = lds[lds_phys(c)];
  }
  crx_rr<8,1>(v, cm1[8].x, cm1[8].y);               // CRX(8,9)  (ctrl w8=r3, tgt w9=r0)
  crx_rr<1,2>(v, cm1[9].x, cm1[9].y);               // CRX(9,10)
  crx_rr<2,4>(v, cm1[10].x, cm1[10].y);             // CRX(10,11)
  __syncthreads();
  // T3: C -> D (write layout)
  #pragma unroll
  for (int r=0;r<16;r++){
    int c = (lane&63) | (wv<<6) | (((r>>3)&1)<<8) | ((r&7)<<9);
    lds[lds_phys(c)] = v[r];
  }
  __syncthreads();
  float2* outp = compact + ((size_t)bg<<12);
  #pragma unroll
  for (int r=0;r<16;r++){
    int c = ((lane>>1)&31) | (wv<<5) | (r<<7) | ((lane&1)<<11);
    outp[lane | (wv<<6) | (r<<8)] = lds[lds_phys(c)];
  }
}

// ---------------------------------------------------------------------------
// PASS 2: 16 blocks/sample, h = wires {7,8,9,10}.
// Canonical c bits = [w0..w6 -> c0..c6, w11..w15 -> c7..c11]
// Stage A: r={12,13,14,15} lane={11,0,1,2,3,4} wv={5,6}
// Stage B: r={0,1,2,3} lane={15,4,5,6,11,12} wv={13,14}
// Stage C: r={4,5,6,15} lane={0,1,11,12,13,3} wv={2,14}
// st addr bits: [0]=w0 [1]=w1 [2]=w11 [3]=w12 [4]=w13 [5]=w3 [6]=w2 [7]=w14
//               [8]=w4 [9]=w5 [10]=w6 [11]=w15 [12..15]=w7..w10
__global__ __launch_bounds__(256) void kpass2(const float2* __restrict__ compact,
      const float2* __restrict__ fU1, const float2* __restrict__ fU2,
      const float2* __restrict__ cm1, const float2* __restrict__ cm2,
      float2* __restrict__ st, int b0)
{
  int lane = threadIdx.x & 63;
  int wv = threadIdx.x >> 6;
  int blk = blockIdx.x;
  int bl = blk >> 4, h = blk & 15;
  int bg = b0 + bl;
  const float2* U1 = fU1 + ((size_t)bg<<6);
  const float2* U2 = fU2 + ((size_t)bg<<6);
  // single coalesced load per thread
  float2 a = compact[((size_t)bg<<12) | (size_t)(lane | (wv<<6) | (h<<8))];
  // v[r] = a * V12[r0]*V13[r1]*V14[r2]*V15[r3]  (layer-1 prefactor)
  float2 v[16];
  v[0] = cmulc(a, U1[48]);  v[1] = cmulc(a, U1[50]);
  v[2] = cmulc(v[0], U1[54]); v[3] = cmulc(v[1], U1[54]);
  v[0] = cmulc(v[0], U1[52]); v[1] = cmulc(v[1], U1[52]);
  #pragma unroll
  for (int i=0;i<4;i++){ v[i+4]=cmulc(v[i],U1[58]); v[i]=cmulc(v[i],U1[56]); }
  #pragma unroll
  for (int i=0;i<8;i++){ v[i+8]=cmulc(v[i],U1[62]); v[i]=cmulc(v[i],U1[60]); }
  // Stage A: L1 tail CRX
  crx_pred<1>(v, (lane&1)!=0, cm1[11].x, cm1[11].y); // CRX(11,12) ctrl w11=l0
  crx_rr<1,2>(v, cm1[12].x, cm1[12].y);              // CRX(12,13)
  crx_rr<2,4>(v, cm1[13].x, cm1[13].y);              // CRX(13,14)
  crx_rr<4,8>(v, cm1[14].x, cm1[14].y);              // CRX(14,15)
  __shared__ float2 lds[4096];
  // T1: A -> B
  #pragma unroll
  for (int r=0;r<16;r++){
    int c = ((lane>>1)&31) | (wv<<5) | ((lane&1)<<7) | (r<<8);
    lds[lds_phys(c)] = v[r];
  }
  __syncthreads();
  #pragma unroll
  for (int r=0;r<16;r++){
    int c = r | (((lane>>1)&31)<<4) | (wv<<9) | ((lane&1)<<11);
    v[r] = lds[lds_phys(c)];
  }
  crx_pred<1>(v, (lane&1)!=0, cm1[15].x, cm1[15].y); // CRX(15,0) ctrl w15=l0
  reg_gate<1>(v, U2[0], U2[1], U2[2], U2[3]);        // W0
  reg_gate<2>(v, U2[4], U2[5], U2[6], U2[7]);        // W1
  reg_gate<4>(v, U2[8], U2[9], U2[10],U2[11]);       // W2
  reg_gate<8>(v, U2[12],U2[13],U2[14],U2[15]);       // W3
  crx_rr<1,2>(v, cm2[0].x, cm2[0].y);                // L2 CRX(0,1)
  crx_rr<2,4>(v, cm2[1].x, cm2[1].y);                // L2 CRX(1,2)
  crx_rr<4,8>(v, cm2[2].x, cm2[2].y);                // L2 CRX(2,3)
  __syncthreads();
  // T2: B -> C
  #pragma unroll
  for (int r=0;r<16;r++){
    int c = r | (((lane>>1)&31)<<4) | (wv<<9) | ((lane&1)<<11);
    lds[lds_phys(c)] = v[r];
  }
  __syncthreads();
  #pragma unroll
  for (int r=0;r<16;r++){
    int c = (lane&3) | ((wv&1)<<2) | (((lane>>5)&1)<<3) | ((r&7)<<4)
          | (((lane>>2)&7)<<7) | (((wv>>1)&1)<<10) | (((r>>3)&1)<<11);
    v[r] = lds[lds_phys(c)];
  }
  reg_gate<1>(v, U2[16],U2[17],U2[18],U2[19]);       // W4
  reg_gate<2>(v, U2[20],U2[21],U2[22],U2[23]);       // W5
  reg_gate<4>(v, U2[24],U2[25],U2[26],U2[27]);       // W6
  crx_pred<1>(v, ((lane>>5)&1)!=0, cm2[3].x, cm2[3].y); // L2 CRX(3,4) ctrl w3=l5
  crx_rr<1,2>(v, cm2[4].x, cm2[4].y);                // L2 CRX(4,5)
  crx_rr<2,4>(v, cm2[5].x, cm2[5].y);                // L2 CRX(5,6)
  float2* S = st + ((size_t)bl<<16);
  #pragma unroll
  for (int r=0;r<16;r++){
    S[lane | (wv<<6) | (r<<8) | (h<<12)] = v[r];
  }
}

// ---------------------------------------------------------------------------
// PASS 3: 16 blocks/sample, h = wires {2,3,4,5}.
// Canonical c bits = [w0,w1 -> c0,c1, w6..w10 -> c2..c6, w11..w15 -> c7..c11]
// Stage A: r={7,8,9,10} lane={0,1,11,12,13,14} wv={6,15}
// Stage B: r={11,12,13,14} lane={10,0,1,7,8,9} wv={6,15}
// Stage C: r={15,0,1,6} lane={7,8,9,10,13,14} wv={11,12}
__global__ __launch_bounds__(256) void kpass3(const float2* __restrict__ st,
      const float2* __restrict__ fU2, const float2* __restrict__ cm2,
      float* __restrict__ expv, int b0)
{
  int lane = threadIdx.x & 63;
  int wv = threadIdx.x >> 6;
  int blk = blockIdx.x;
  int bl = blk >> 4, h = blk & 15;
  int bg = b0 + bl;
  const float2* S = st + ((size_t)bl<<16);
  const float2* U2 = fU2 + ((size_t)bg<<6);
  int abase = (((h>>1)&1)<<5) | ((h&1)<<6) | (((h>>2)&1)<<8) | (((h>>3)&1)<<9)
            | ((wv&1)<<10) | (((wv>>1)&1)<<11);
  float2 v[16];
  #pragma unroll
  for (int r=0;r<16;r++){
    v[r] = S[(lane&31) | (((lane>>5)&1)<<7) | abase | (r<<12)];
  }
  reg_gate<1>(v, U2[28],U2[29],U2[30],U2[31]);       // W7
  reg_gate<2>(v, U2[32],U2[33],U2[34],U2[35]);       // W8
  reg_gate<4>(v, U2[36],U2[37],U2[38],U2[39]);       // W9
  reg_gate<8>(v, U2[40],U2[41],U2[42],U2[43]);       // W10
  if (wv & 1) crx_on<1>(v, cm2[6].x, cm2[6].y);      // CRX(6,7) ctrl w6=wv0 (uniform)
  crx_rr<1,2>(v, cm2[7].x, cm2[7].y);                // CRX(7,8)
  crx_rr<2,4>(v, cm2[8].x, cm2[8].y);                // CRX(8,9)
  crx_rr<4,8>(v, cm2[9].x, cm2[9].y);                // CRX(9,10)
  __shared__ float2 lds[4096];
  // T1: A -> B
  #pragma unroll
  for (int r=0;r<16;r++){
    int c = (lane&3) | ((wv&1)<<2) | (r<<3) | (((lane>>2)&15)<<7) | (((wv>>1)&1)<<11);
    lds[lds_phys(c)] = v[r];
  }
  __syncthreads();
  #pragma unroll
  for (int r=0;r<16;r++){
    int c = ((lane>>1)&3) | ((wv&1)<<2) | (((lane>>3)&7)<<3) | ((lane&1)<<6)
          | (r<<7) | (((wv>>1)&1)<<11);
    v[r] = lds[lds_phys(c)];
  }
  reg_gate<1>(v, U2[44],U2[45],U2[46],U2[47]);       // W11
  reg_gate<2>(v, U2[48],U2[49],U2[50],U2[51]);       // W12
  reg_gate<4>(v, U2[52],U2[53],U2[54],U2[55]);       // W13
  reg_gate<8>(v, U2[56],U2[57],U2[58],U2[59]);       // W14
  crx_pred<1>(v, (lane&1)!=0, cm2[10].x, cm2[10].y); // CRX(10,11) ctrl w10=l0
  crx_rr<1,2>(v, cm2[11].x, cm2[11].y);              // CRX(11,12)
  crx_rr<2,4>(v, cm2[12].x, cm2[12].y);              // CRX(12,13)
  crx_rr<4,8>(v, cm2[13].x, cm2[13].y);              // CRX(13,14)
  __syncthreads();
  // T2: B -> C
  #pragma unroll
  for (int r=0;r<16;r++){
    int c = ((lane>>1)&3) | ((wv&1)<<2) | (((lane>>3)&7)<<3) | ((lane&1)<<6)
          | (r<<7) | (((wv>>1)&1)<<11);
    lds[lds_phys(c)] = v[r];
  }
  __syncthreads();
  #pragma unroll
  for (int r=0;r<16;r++){
    int c = ((r>>1)&7) | ((lane&15)<<3) | ((wv&3)<<7) | (((lane>>4)&3)<<9) | ((r&1)<<11);
    v[r] = lds[lds_phys(c)];
  }
  reg_gate<1>(v, U2[60],U2[61],U2[62],U2[63]);       // W15
  crx_pred<1>(v, ((lane>>5)&1)!=0, cm2[14].x, cm2[14].y); // CRX(14,15) ctrl w14=l5
  crx_rr<1,2>(v, cm2[15].x, cm2[15].y);              // CRX(15,0) ctrl w15=r0 tgt w0=r1
  // expvals. regs: w15=m1 w0=m2 w1=m4 w6=m8; lanes l0..l5={7,8,9,10,13,14}; wv={11,12}; h={2,3,4,5}
  float tot=0.f, S0=0.f, S1=0.f, S2=0.f, S3=0.f;
  #pragma unroll
  for (int r=0;r<16;r++){
    float p = v[r].x*v[r].x + v[r].y*v[r].y;
    tot += p;
    if (r&1) S0+=p;
    if (r&2) S1+=p;
    if (r&4) S2+=p;
    if (r&8) S3+=p;
  }
  float s = tot;
  float u[6];
  #pragma unroll
  for (int b=0;b<6;b++){
    int m = 1<<b;
    float t = __shfl_xor(s, m, 64);
    u[b] = s - t;
    s = s + t;
    #pragma unroll
    for (int j=0;j<6;j++) if (j<b) u[j] += __shfl_xor(u[j], m, 64);
  }
  #pragma unroll
  for (int d=1; d<64; d<<=1){
    S0 += __shfl_xor(S0, d, 64);
    S1 += __shfl_xor(S1, d, 64);
    S2 += __shfl_xor(S2, d, 64);
    S3 += __shfl_xor(S3, d, 64);
  }
  __syncthreads();                 // all lds reads done; reuse as ef
  float* ef = (float*)lds;
  if (lane==0){
    ef[wv*16+15]=s-2.f*S0; ef[wv*16+0]=s-2.f*S1; ef[wv*16+1]=s-2.f*S2; ef[wv*16+6]=s-2.f*S3;
    ef[wv*16+7]=u[0]; ef[wv*16+8]=u[1]; ef[wv*16+9]=u[2]; ef[wv*16+10]=u[3];
    ef[wv*16+13]=u[4]; ef[wv*16+14]=u[5];
    ef[wv*16+11]=(wv&1)?-s:s; ef[wv*16+12]=(wv&2)?-s:s;
    ef[wv*16+2]=(h&1)?-s:s; ef[wv*16+3]=(h&2)?-s:s; ef[wv*16+4]=(h&4)?-s:s; ef[wv*16+5]=(h&8)?-s:s;
  }
  __syncthreads();
  if (threadIdx.x < 16){
    float r4 = ef[threadIdx.x]+ef[16+threadIdx.x]+ef[32+threadIdx.x]+ef[48+threadIdx.x];
    atomicAdd(expv + (size_t)bg*NQ + threadIdx.x, r4);
  }
}

__global__ __launch_bounds__(128) void klogits(const float* __restrict__ expv,
      const float* __restrict__ W, const float* __restrict__ bias,
      float* __restrict__ out)
{
  int b = blockIdx.x;
  int tid = threadIdx.x;
  __shared__ float f[NQ];
  __shared__ float lg[NCLS];
  if (tid < NQ) f[tid] = expv[b*NQ + tid];
  __syncthreads();
  if (tid < NCLS){
    float acc = bias[tid];
    #pragma unroll
    for (int i=0;i<NQ;i++) acc += f[i]*W[tid*NQ+i];
    lg[tid] = acc;
  }
  __syncthreads();
  if (tid < NCLS){
    float m = -1e30f;
    for (int i=0;i<NCLS;i++) m = fmaxf(m, lg[i]);
    float sum = 0.f;
    for (int i=0;i<NCLS;i++) sum += expf(lg[i]-m);
    out[b*NCLS+tid] = lg[tid] - m - logf(sum);
  }
}

extern "C" void kernel_launch(void* const* d_in, const int* in_sizes, int n_in,
                              void* d_out, int out_size, void* d_ws, size_t ws_size,
                              hipStream_t stream)
{
  const float* x    = (const float*)d_in[0];
  const float* rot1 = (const float*)d_in[1];
  const float* crx1 = (const float*)d_in[2];
  const float* rot2 = (const float*)d_in[3];
  const float* crx2 = (const float*)d_in[4];
  const float* W    = (const float*)d_in[5];
  const float* bias = (const float*)d_in[6];
  float* out = (float*)d_out;

  char* ws = (char*)d_ws;
  float*  expv = (float*)ws;                          // 32 KB
  float2* fU   = (float2*)(ws + (40<<10));            // 512 KB
  float2* cmm  = (float2*)(ws + (560<<10));           // 256 B
  float2* compact = (float2*)(ws + (576<<10));        // 16 MB
  const size_t stOff = (size_t)(576<<10) + ((size_t)NBATCH<<15);
  float2* st   = (float2*)(ws + stOff);

  hipMemsetAsync(expv, 0, NBATCH*NQ*sizeof(float), stream);
  kprep<<<(2*NBATCH*NQ + 255)/256, 256, 0, stream>>>(x, rot1, crx1, rot2, crx2, fU, cmm);

  float2* fU1 = fU;
  float2* fU2 = fU + 32768;
  float2* cm1 = cmm;
  float2* cm2 = cmm + 16;

  kpass1<<<NBATCH, 256, 0, stream>>>(fU1, cm1, compact);

  size_t avail = (ws_size > stOff) ? (ws_size - stOff) : 0;
  int chunk = NBATCH;
  while (chunk > 1 && (size_t)chunk*65536*sizeof(float2) > avail) chunk >>= 1;

  for (int b0 = 0; b0 < NBATCH; b0 += chunk){
    kpass2<<<chunk*16, 256, 0, stream>>>(compact, fU1, fU2, cm1, cm2, st, b0);
    kpass3<<<chunk*16, 256, 0, stream>>>(st, fU2, cm2, expv, b0);
  }
  klogits<<<NBATCH, 128, 0, stream>>>(expv, W, bias, out);
}

// Round 4
// 207.436 us; speedup vs baseline: 2.4489x; 1.3672x over previous
//
#include <hip/hip_runtime.h>
#include <math.h>

#define NQ 16
#define NBATCH 512
#define NCLS 100

typedef float v2f __attribute__((ext_vector_type(2)));

__device__ __forceinline__ v2f mkv(float x, float y){ v2f r; r.x = x; r.y = y; return r; }

// ---- packed-f32 complex primitives (VOP3P v_pk_*, 2 FP32 lanes per instr) ----
// complex multiply d = a*b : d.lo = a.x*b.x - a.y*b.y ; d.hi = a.x*b.y + a.y*b.x
__device__ __forceinline__ v2f pk_cmul(v2f a, v2f b){
  v2f t, d;
  asm("v_pk_mul_f32 %0, %1, %2 op_sel:[0,0] op_sel_hi:[1,0]"
      : "=v"(t) : "v"(a), "v"(b));
  asm("v_pk_fma_f32 %0, %1, %2, %3 op_sel:[1,1,0] op_sel_hi:[0,1,1] neg_lo:[1,0,0]"
      : "=v"(d) : "v"(a), "v"(b), "v"(t));
  return d;
}
// complex multiply-accumulate d = a*b + acc
__device__ __forceinline__ v2f pk_cmul_acc(v2f a, v2f b, v2f acc){
  v2f t, d;
  asm("v_pk_fma_f32 %0, %1, %2, %3 op_sel:[0,0,0] op_sel_hi:[1,0,1]"
      : "=v"(t) : "v"(a), "v"(b), "v"(acc));
  asm("v_pk_fma_f32 %0, %1, %2, %3 op_sel:[1,1,0] op_sel_hi:[0,1,1] neg_lo:[1,0,0]"
      : "=v"(d) : "v"(a), "v"(b), "v"(t));
  return d;
}
// RX pair rotation with cs=(c,s):
// a' = (c*a.x + s*b.y, c*a.y - s*b.x) ; b' = (s*a.y + c*b.x, -s*a.x + c*b.y)
__device__ __forceinline__ void pk_rx(v2f &a, v2f &b, v2f cs){
  v2f t1, t2, na, nb;
  asm("v_pk_mul_f32 %0, %1, %2 op_sel:[0,0] op_sel_hi:[0,1]"
      : "=v"(t1) : "v"(cs), "v"(a));
  asm("v_pk_mul_f32 %0, %1, %2 op_sel:[0,0] op_sel_hi:[0,1]"
      : "=v"(t2) : "v"(cs), "v"(b));
  asm("v_pk_fma_f32 %0, %1, %2, %3 op_sel:[1,1,0] op_sel_hi:[1,0,1] neg_hi:[0,1,0]"
      : "=v"(na) : "v"(cs), "v"(b), "v"(t1));
  asm("v_pk_fma_f32 %0, %1, %2, %3 op_sel:[1,1,0] op_sel_hi:[1,0,1] neg_hi:[0,1,0]"
      : "=v"(nb) : "v"(cs), "v"(a), "v"(t2));
  a = na; b = nb;
}

// CRX with per-lane predicate ctrl (off -> identity, exact)
template<int MT>
__device__ __forceinline__ void crx_pred(v2f (&v)[16], bool on, v2f cs){
  v2f id = mkv(1.f, 0.f);
  v2f cs_p = on ? cs : id;
  #pragma unroll
  for (int r=0;r<16;r++) if(!(r&MT)) pk_rx(v[r], v[r|MT], cs_p);
}
// CRX applied unconditionally (call under wave-uniform branch)
template<int MT>
__device__ __forceinline__ void crx_on(v2f (&v)[16], v2f cs){
  #pragma unroll
  for (int r=0;r<16;r++) if(!(r&MT)) pk_rx(v[r], v[r|MT], cs);
}
// CRX ctrl and tgt both register bits
template<int MC,int MT>
__device__ __forceinline__ void crx_rr(v2f (&v)[16], v2f cs){
  #pragma unroll
  for (int r=0;r<16;r++) if((r&MC)&&!(r&MT)) pk_rx(v[r], v[r|MT], cs);
}
// full 1q gate on register bit M
template<int M>
__device__ __forceinline__ void reg_gate(v2f (&v)[16], v2f u00, v2f u01, v2f u10, v2f u11){
  #pragma unroll
  for (int r=0;r<16;r++) if(!(r&M)){
    v2f a = v[r], b = v[r|M];
    v[r]   = pk_cmul_acc(u01, b, pk_cmul(u00, a));
    v[r|M] = pk_cmul_acc(u11, b, pk_cmul(u10, a));
  }
}

__device__ __forceinline__ int lds_phys(int c){ return c ^ (((c>>4)^(c>>8))&15); }

// Precompute fused U_i^b = Rot_i * RX(x[b,i]) for both layers, + CRX (c,s)
__global__ __launch_bounds__(256) void kprep(const float* __restrict__ x,
      const float* __restrict__ rot1, const float* __restrict__ crx1,
      const float* __restrict__ rot2, const float* __restrict__ crx2,
      v2f* __restrict__ fU, v2f* __restrict__ cm)
{
  int t = blockIdx.x*blockDim.x + threadIdx.x;
  if (t < 2*NBATCH*NQ){
    int w  = t & 15;
    int bb = (t>>4) & (NBATCH-1);
    int L  = t >> 13;
    const float* rot = L ? rot2 : rot1;
    float phi = rot[w*3+0], th = rot[w*3+1], om = rot[w*3+2];
    float ct = cosf(0.5f*th), stt = sinf(0.5f*th);
    float a1 = 0.5f*(phi+om), a2 = 0.5f*(phi-om);
    float emx = cosf(a1), emy = -sinf(a1);
    float epx = cosf(a1), epy =  sinf(a1);
    float edmx = cosf(a2), edmy = -sinf(a2);
    float edpx = cosf(a2), edpy =  sinf(a2);
    float R00x = emx*ct,   R00y = emy*ct;
    float R01x = -edpx*stt, R01y = -edpy*stt;
    float R10x = edmx*stt, R10y = edmy*stt;
    float R11x = epx*ct,   R11y = epy*ct;
    float xv = x[bb*NQ + w];
    float cx = cosf(0.5f*xv), sx = sinf(0.5f*xv);
    v2f* o = fU + (size_t)t*4;
    o[0] = mkv(R00x*cx + R01y*sx,  R00y*cx - R01x*sx);
    o[1] = mkv(R00y*sx + R01x*cx, -R00x*sx + R01y*cx);
    o[2] = mkv(R10x*cx + R11y*sx,  R10y*cx - R11x*sx);
    o[3] = mkv(R10y*sx + R11x*cx, -R10x*sx + R11y*cx);
  }
  if (t < 2*NQ){
    int L = t>>4, w = t&15;
    const float* cxl = L ? crx2 : crx1;
    float thc = cxl[w];
    cm[t] = mkv(cosf(0.5f*thc), sinf(0.5f*thc));
  }
}

// ---------------------------------------------------------------------------
// PASS 1: one block/sample. Product state wires 0..11 + L1 CRX(0,1)..(10,11).
// Stage A: r={1,2,3,4} lane={0,5,6,7,8,9} wv={10,11}
// Stage B: r={5,6,7,8} lane={4,0,1,2,3,9} wv={10,11}
// Stage C: r={9,10,11,8} lane={0,1,2,3,4,5} wv={6,7}
// compact addr bits: [0..5]={11,0,1,2,3,4} [6,7]={5,6} [8..11]={7,8,9,10}
__global__ __launch_bounds__(256) void kpass1(const v2f* __restrict__ fU1,
      const v2f* __restrict__ cm1, v2f* __restrict__ compact)
{
  int lane = threadIdx.x & 63;
  int wv = threadIdx.x >> 6;
  int bg = blockIdx.x;
  const v2f* U = fU1 + ((size_t)bg<<6);
  v2f a = (lane&1) ? U[2] : U[0];                       // V0
  a = pk_cmul(a, ((lane>>1)&1) ? U[22] : U[20]);        // V5
  a = pk_cmul(a, ((lane>>2)&1) ? U[26] : U[24]);        // V6
  a = pk_cmul(a, ((lane>>3)&1) ? U[30] : U[28]);        // V7
  a = pk_cmul(a, ((lane>>4)&1) ? U[34] : U[32]);        // V8
  a = pk_cmul(a, ((lane>>5)&1) ? U[38] : U[36]);        // V9
  a = pk_cmul(a, (wv&1) ? U[42] : U[40]);               // V10
  a = pk_cmul(a, ((wv>>1)&1) ? U[46] : U[44]);          // V11
  v2f v[16];
  v[0] = pk_cmul(a, U[4]);    v[1] = pk_cmul(a, U[6]);     // V1
  v[2] = pk_cmul(v[0], U[10]); v[3] = pk_cmul(v[1], U[10]);
  v[0] = pk_cmul(v[0], U[8]);  v[1] = pk_cmul(v[1], U[8]); // V2
  #pragma unroll
  for (int i=0;i<4;i++){ v[i+4]=pk_cmul(v[i],U[14]); v[i]=pk_cmul(v[i],U[12]); } // V3
  #pragma unroll
  for (int i=0;i<8;i++){ v[i+8]=pk_cmul(v[i],U[18]); v[i]=pk_cmul(v[i],U[16]); } // V4
  crx_pred<1>(v, (lane&1)!=0, cm1[0]);  // CRX(0,1)
  crx_rr<1,2>(v, cm1[1]);               // CRX(1,2)
  crx_rr<2,4>(v, cm1[2]);               // CRX(2,3)
  crx_rr<4,8>(v, cm1[3]);               // CRX(3,4)
  __shared__ v2f lds[4096];
  // T1: A -> B
  #pragma unroll
  for (int r=0;r<16;r++){
    int c = (lane&1) | (r<<1) | (((lane>>1)&31)<<5) | (wv<<10);
    lds[lds_phys(c)] = v[r];
  }
  __syncthreads();
  #pragma unroll
  for (int r=0;r<16;r++){
    int c = ((lane>>1)&15) | ((lane&1)<<4) | (r<<5) | (((lane>>5)&1)<<9) | (wv<<10);
    v[r] = lds[lds_phys(c)];
  }
  crx_pred<1>(v, (lane&1)!=0, cm1[4]);  // CRX(4,5)
  crx_rr<1,2>(v, cm1[5]);               // CRX(5,6)
  crx_rr<2,4>(v, cm1[6]);               // CRX(6,7)
  crx_rr<4,8>(v, cm1[7]);               // CRX(7,8)
  __syncthreads();
  // T2: B -> C
  #pragma unroll
  for (int r=0;r<16;r++){
    int c = ((lane>>1)&15) | ((lane&1)<<4) | (r<<5) | (((lane>>5)&1)<<9) | (wv<<10);
    lds[lds_phys(c)] = v[r];
  }
  __syncthreads();
  #pragma unroll
  for (int r=0;r<16;r++){
    int c = (lane&63) | (wv<<6) | (((r>>3)&1)<<8) | ((r&7)<<9);
    v[r] = lds[lds_phys(c)];
  }
  crx_rr<8,1>(v, cm1[8]);               // CRX(8,9)
  crx_rr<1,2>(v, cm1[9]);               // CRX(9,10)
  crx_rr<2,4>(v, cm1[10]);              // CRX(10,11)
  __syncthreads();
  // T3: C -> D (write layout)
  #pragma unroll
  for (int r=0;r<16;r++){
    int c = (lane&63) | (wv<<6) | (((r>>3)&1)<<8) | ((r&7)<<9);
    lds[lds_phys(c)] = v[r];
  }
  __syncthreads();
  v2f* outp = compact + ((size_t)bg<<12);
  #pragma unroll
  for (int r=0;r<16;r++){
    int c = ((lane>>1)&31) | (wv<<5) | (r<<7) | ((lane&1)<<11);
    outp[lane | (wv<<6) | (r<<8)] = lds[lds_phys(c)];
  }
}

// ---------------------------------------------------------------------------
// PASS 2: 16 blocks/sample, h = wires {7,8,9,10}.
// Stage A: r={12,13,14,15} lane={11,0,1,2,3,4} wv={5,6}
// Stage B: r={0,1,2,3} lane={15,4,5,6,11,12} wv={13,14}
// Stage C: r={4,5,6,15} lane={0,1,11,12,13,3} wv={2,14}
// st addr bits: [0]=w0 [1]=w1 [2]=w11 [3]=w12 [4]=w13 [5]=w3 [6]=w2 [7]=w14
//               [8]=w4 [9]=w5 [10]=w6 [11]=w15 [12..15]=w7..w10
__global__ __launch_bounds__(256) void kpass2(const v2f* __restrict__ compact,
      const v2f* __restrict__ fU1, const v2f* __restrict__ fU2,
      const v2f* __restrict__ cm1, const v2f* __restrict__ cm2,
      v2f* __restrict__ st, int b0)
{
  int lane = threadIdx.x & 63;
  int wv = threadIdx.x >> 6;
  int blk = blockIdx.x;
  int bl = blk >> 4, h = blk & 15;
  int bg = b0 + bl;
  const v2f* U1 = fU1 + ((size_t)bg<<6);
  const v2f* U2 = fU2 + ((size_t)bg<<6);
  v2f a = compact[((size_t)bg<<12) | (size_t)(lane | (wv<<6) | (h<<8))];
  v2f v[16];
  v[0] = pk_cmul(a, U1[48]);   v[1] = pk_cmul(a, U1[50]);
  v[2] = pk_cmul(v[0], U1[54]); v[3] = pk_cmul(v[1], U1[54]);
  v[0] = pk_cmul(v[0], U1[52]); v[1] = pk_cmul(v[1], U1[52]);
  #pragma unroll
  for (int i=0;i<4;i++){ v[i+4]=pk_cmul(v[i],U1[58]); v[i]=pk_cmul(v[i],U1[56]); }
  #pragma unroll
  for (int i=0;i<8;i++){ v[i+8]=pk_cmul(v[i],U1[62]); v[i]=pk_cmul(v[i],U1[60]); }
  crx_pred<1>(v, (lane&1)!=0, cm1[11]); // CRX(11,12)
  crx_rr<1,2>(v, cm1[12]);              // CRX(12,13)
  crx_rr<2,4>(v, cm1[13]);              // CRX(13,14)
  crx_rr<4,8>(v, cm1[14]);              // CRX(14,15)
  __shared__ v2f lds[4096];
  // T1: A -> B
  #pragma unroll
  for (int r=0;r<16;r++){
    int c = ((lane>>1)&31) | (wv<<5) | ((lane&1)<<7) | (r<<8);
    lds[lds_phys(c)] = v[r];
  }
  __syncthreads();
  #pragma unroll
  for (int r=0;r<16;r++){
    int c = r | (((lane>>1)&31)<<4) | (wv<<9) | ((lane&1)<<11);
    v[r] = lds[lds_phys(c)];
  }
  crx_pred<1>(v, (lane&1)!=0, cm1[15]); // CRX(15,0)
  reg_gate<1>(v, U2[0], U2[1], U2[2], U2[3]);        // W0
  reg_gate<2>(v, U2[4], U2[5], U2[6], U2[7]);        // W1
  reg_gate<4>(v, U2[8], U2[9], U2[10],U2[11]);       // W2
  reg_gate<8>(v, U2[12],U2[13],U2[14],U2[15]);       // W3
  crx_rr<1,2>(v, cm2[0]);               // L2 CRX(0,1)
  crx_rr<2,4>(v, cm2[1]);               // L2 CRX(1,2)
  crx_rr<4,8>(v, cm2[2]);               // L2 CRX(2,3)
  __syncthreads();
  // T2: B -> C
  #pragma unroll
  for (int r=0;r<16;r++){
    int c = r | (((lane>>1)&31)<<4) | (wv<<9) | ((lane&1)<<11);
    lds[lds_phys(c)] = v[r];
  }
  __syncthreads();
  #pragma unroll
  for (int r=0;r<16;r++){
    int c = (lane&3) | ((wv&1)<<2) | (((lane>>5)&1)<<3) | ((r&7)<<4)
          | (((lane>>2)&7)<<7) | (((wv>>1)&1)<<10) | (((r>>3)&1)<<11);
    v[r] = lds[lds_phys(c)];
  }
  reg_gate<1>(v, U2[16],U2[17],U2[18],U2[19]);       // W4
  reg_gate<2>(v, U2[20],U2[21],U2[22],U2[23]);       // W5
  reg_gate<4>(v, U2[24],U2[25],U2[26],U2[27]);       // W6
  crx_pred<1>(v, ((lane>>5)&1)!=0, cm2[3]);          // L2 CRX(3,4)
  crx_rr<1,2>(v, cm2[4]);               // L2 CRX(4,5)
  crx_rr<2,4>(v, cm2[5]);               // L2 CRX(5,6)
  v2f* S = st + ((size_t)bl<<16);
  #pragma unroll
  for (int r=0;r<16;r++){
    S[lane | (wv<<6) | (r<<8) | (h<<12)] = v[r];
  }
}

// ---------------------------------------------------------------------------
// PASS 3: 16 blocks/sample, h = wires {2,3,4,5}.
// Stage A: r={7,8,9,10} lane={0,1,11,12,13,14} wv={6,15}
// Stage B: r={11,12,13,14} lane={10,0,1,7,8,9} wv={6,15}
// Stage C: r={15,0,1,6} lane={7,8,9,10,13,14} wv={11,12}
__global__ __launch_bounds__(256) void kpass3(const v2f* __restrict__ st,
      const v2f* __restrict__ fU2, const v2f* __restrict__ cm2,
      float* __restrict__ expv, int b0)
{
  int lane = threadIdx.x & 63;
  int wv = threadIdx.x >> 6;
  int blk = blockIdx.x;
  int bl = blk >> 4, h = blk & 15;
  int bg = b0 + bl;
  const v2f* S = st + ((size_t)bl<<16);
  const v2f* U2 = fU2 + ((size_t)bg<<6);
  int abase = (((h>>1)&1)<<5) | ((h&1)<<6) | (((h>>2)&1)<<8) | (((h>>3)&1)<<9)
            | ((wv&1)<<10) | (((wv>>1)&1)<<11);
  v2f v[16];
  #pragma unroll
  for (int r=0;r<16;r++){
    v[r] = S[(lane&31) | (((lane>>5)&1)<<7) | abase | (r<<12)];
  }
  reg_gate<1>(v, U2[28],U2[29],U2[30],U2[31]);       // W7
  reg_gate<2>(v, U2[32],U2[33],U2[34],U2[35]);       // W8
  reg_gate<4>(v, U2[36],U2[37],U2[38],U2[39]);       // W9
  reg_gate<8>(v, U2[40],U2[41],U2[42],U2[43]);       // W10
  if (wv & 1) crx_on<1>(v, cm2[6]);                  // CRX(6,7) ctrl w6=wv0 (uniform)
  crx_rr<1,2>(v, cm2[7]);               // CRX(7,8)
  crx_rr<2,4>(v, cm2[8]);               // CRX(8,9)
  crx_rr<4,8>(v, cm2[9]);               // CRX(9,10)
  __shared__ v2f lds[4096];
  // T1: A -> B
  #pragma unroll
  for (int r=0;r<16;r++){
    int c = (lane&3) | ((wv&1)<<2) | (r<<3) | (((lane>>2)&15)<<7) | (((wv>>1)&1)<<11);
    lds[lds_phys(c)] = v[r];
  }
  __syncthreads();
  #pragma unroll
  for (int r=0;r<16;r++){
    int c = ((lane>>1)&3) | ((wv&1)<<2) | (((lane>>3)&7)<<3) | ((lane&1)<<6)
          | (r<<7) | (((wv>>1)&1)<<11);
    v[r] = lds[lds_phys(c)];
  }
  reg_gate<1>(v, U2[44],U2[45],U2[46],U2[47]);       // W11
  reg_gate<2>(v, U2[48],U2[49],U2[50],U2[51]);       // W12
  reg_gate<4>(v, U2[52],U2[53],U2[54],U2[55]);       // W13
  reg_gate<8>(v, U2[56],U2[57],U2[58],U2[59]);       // W14
  crx_pred<1>(v, (lane&1)!=0, cm2[10]);              // CRX(10,11)
  crx_rr<1,2>(v, cm2[11]);              // CRX(11,12)
  crx_rr<2,4>(v, cm2[12]);              // CRX(12,13)
  crx_rr<4,8>(v, cm2[13]);              // CRX(13,14)
  __syncthreads();
  // T2: B -> C
  #pragma unroll
  for (int r=0;r<16;r++){
    int c = ((lane>>1)&3) | ((wv&1)<<2) | (((lane>>3)&7)<<3) | ((lane&1)<<6)
          | (r<<7) | (((wv>>1)&1)<<11);
    lds[lds_phys(c)] = v[r];
  }
  __syncthreads();
  #pragma unroll
  for (int r=0;r<16;r++){
    int c = ((r>>1)&7) | ((lane&15)<<3) | ((wv&3)<<7) | (((lane>>4)&3)<<9) | ((r&1)<<11);
    v[r] = lds[lds_phys(c)];
  }
  reg_gate<1>(v, U2[60],U2[61],U2[62],U2[63]);       // W15
  crx_pred<1>(v, ((lane>>5)&1)!=0, cm2[14]);         // CRX(14,15)
  crx_rr<1,2>(v, cm2[15]);              // CRX(15,0)
  // expvals. regs: w15=m1 w0=m2 w1=m4 w6=m8; lanes l0..l5={7,8,9,10,13,14}; wv={11,12}; h={2,3,4,5}
  float tot=0.f, S0=0.f, S1=0.f, S2=0.f, S3=0.f;
  #pragma unroll
  for (int r=0;r<16;r++){
    float p = v[r].x*v[r].x + v[r].y*v[r].y;
    tot += p;
    if (r&1) S0+=p;
    if (r&2) S1+=p;
    if (r&4) S2+=p;
    if (r&8) S3+=p;
  }
  float s = tot;
  float u[6];
  #pragma unroll
  for (int b=0;b<6;b++){
    int m = 1<<b;
    float t = __shfl_xor(s, m, 64);
    u[b] = s - t;
    s = s + t;
    #pragma unroll
    for (int j=0;j<6;j++) if (j<b) u[j] += __shfl_xor(u[j], m, 64);
  }
  #pragma unroll
  for (int d=1; d<64; d<<=1){
    S0 += __shfl_xor(S0, d, 64);
    S1 += __shfl_xor(S1, d, 64);
    S2 += __shfl_xor(S2, d, 64);
    S3 += __shfl_xor(S3, d, 64);
  }
  __syncthreads();
  float* ef = (float*)lds;
  if (lane==0){
    ef[wv*16+15]=s-2.f*S0; ef[wv*16+0]=s-2.f*S1; ef[wv*16+1]=s-2.f*S2; ef[wv*16+6]=s-2.f*S3;
    ef[wv*16+7]=u[0]; ef[wv*16+8]=u[1]; ef[wv*16+9]=u[2]; ef[wv*16+10]=u[3];
    ef[wv*16+13]=u[4]; ef[wv*16+14]=u[5];
    ef[wv*16+11]=(wv&1)?-s:s; ef[wv*16+12]=(wv&2)?-s:s;
    ef[wv*16+2]=(h&1)?-s:s; ef[wv*16+3]=(h&2)?-s:s; ef[wv*16+4]=(h&4)?-s:s; ef[wv*16+5]=(h&8)?-s:s;
  }
  __syncthreads();
  if (threadIdx.x < 16){
    float r4 = ef[threadIdx.x]+ef[16+threadIdx.x]+ef[32+threadIdx.x]+ef[48+threadIdx.x];
    atomicAdd(expv + (size_t)bg*NQ + threadIdx.x, r4);
  }
}

__global__ __launch_bounds__(128) void klogits(const float* __restrict__ expv,
      const float* __restrict__ W, const float* __restrict__ bias,
      float* __restrict__ out)
{
  int b = blockIdx.x;
  int tid = threadIdx.x;
  __shared__ float f[NQ];
  __shared__ float lg[NCLS];
  if (tid < NQ) f[tid] = expv[b*NQ + tid];
  __syncthreads();
  if (tid < NCLS){
    float acc = bias[tid];
    #pragma unroll
    for (int i=0;i<NQ;i++) acc += f[i]*W[tid*NQ+i];
    lg[tid] = acc;
  }
  __syncthreads();
  if (tid < NCLS){
    float m = -1e30f;
    for (int i=0;i<NCLS;i++) m = fmaxf(m, lg[i]);
    float sum = 0.f;
    for (int i=0;i<NCLS;i++) sum += expf(lg[i]-m);
    out[b*NCLS+tid] = lg[tid] - m - logf(sum);
  }
}

extern "C" void kernel_launch(void* const* d_in, const int* in_sizes, int n_in,
                              void* d_out, int out_size, void* d_ws, size_t ws_size,
                              hipStream_t stream)
{
  const float* x    = (const float*)d_in[0];
  const float* rot1 = (const float*)d_in[1];
  const float* crx1 = (const float*)d_in[2];
  const float* rot2 = (const float*)d_in[3];
  const float* crx2 = (const float*)d_in[4];
  const float* W    = (const float*)d_in[5];
  const float* bias = (const float*)d_in[6];
  float* out = (float*)d_out;

  char* ws = (char*)d_ws;
  float* expv = (float*)ws;                        // 32 KB
  v2f*   fU   = (v2f*)(ws + (40<<10));             // 512 KB
  v2f*   cmm  = (v2f*)(ws + (560<<10));            // 256 B
  v2f*   compact = (v2f*)(ws + (576<<10));         // 16 MB
  const size_t stOff = (size_t)(576<<10) + ((size_t)NBATCH<<15);
  v2f*   st   = (v2f*)(ws + stOff);

  hipMemsetAsync(expv, 0, NBATCH*NQ*sizeof(float), stream);
  kprep<<<(2*NBATCH*NQ + 255)/256, 256, 0, stream>>>(x, rot1, crx1, rot2, crx2, fU, cmm);

  v2f* fU1 = fU;
  v2f* fU2 = fU + 32768;
  v2f* cm1 = cmm;
  v2f* cm2 = cmm + 16;

  kpass1<<<NBATCH, 256, 0, stream>>>(fU1, cm1, compact);

  size_t avail = (ws_size > stOff) ? (ws_size - stOff) : 0;
  int chunk = NBATCH;
  while (chunk > 1 && (size_t)chunk*65536*sizeof(v2f) > avail) chunk >>= 1;

  for (int b0 = 0; b0 < NBATCH; b0 += chunk){
    kpass2<<<chunk*16, 256, 0, stream>>>(compact, fU1, fU2, cm1, cm2, st, b0);
    kpass3<<<chunk*16, 256, 0, stream>>>(st, fU2, cm2, expv, b0);
  }
  klogits<<<NBATCH, 128, 0, stream>>>(expv, W, bias, out);
}

// Round 7
// 171.956 us; speedup vs baseline: 2.9542x; 1.2063x over previous
//
#include <hip/hip_runtime.h>
#include <math.h>

#define NQ 16
#define NBATCH 512
#define NCLS 100

typedef float v2f __attribute__((ext_vector_type(2)));
typedef __fp16 f16x2 __attribute__((ext_vector_type(2)));

__device__ __forceinline__ v2f mkv(float x, float y){ v2f r; r.x = x; r.y = y; return r; }
__device__ __forceinline__ f16x2 pack_h(v2f a){ return __builtin_amdgcn_cvt_pkrtz(a.x, a.y); }
__device__ __forceinline__ v2f unpack_h(f16x2 h){ return mkv((float)h.x, (float)h.y); }

// ---- packed-f32 complex primitives (VOP3P v_pk_*) ----
__device__ __forceinline__ v2f pk_cmul(v2f a, v2f b){
  v2f t, d;
  asm("v_pk_mul_f32 %0, %1, %2 op_sel:[0,0] op_sel_hi:[1,0]"
      : "=v"(t) : "v"(a), "v"(b));
  asm("v_pk_fma_f32 %0, %1, %2, %3 op_sel:[1,1,0] op_sel_hi:[0,1,1] neg_lo:[1,0,0]"
      : "=v"(d) : "v"(a), "v"(b), "v"(t));
  return d;
}
__device__ __forceinline__ v2f pk_cmul_acc(v2f a, v2f b, v2f acc){
  v2f t, d;
  asm("v_pk_fma_f32 %0, %1, %2, %3 op_sel:[0,0,0] op_sel_hi:[1,0,1]"
      : "=v"(t) : "v"(a), "v"(b), "v"(acc));
  asm("v_pk_fma_f32 %0, %1, %2, %3 op_sel:[1,1,0] op_sel_hi:[0,1,1] neg_lo:[1,0,0]"
      : "=v"(d) : "v"(a), "v"(b), "v"(t));
  return d;
}
// RX pair rotation with cs=(c,s):
// a' = (c*a.x + s*b.y, c*a.y - s*b.x) ; b' = (s*a.y + c*b.x, -s*a.x + c*b.y)
__device__ __forceinline__ void pk_rx(v2f &a, v2f &b, v2f cs){
  v2f t1, t2, na, nb;
  asm("v_pk_mul_f32 %0, %1, %2 op_sel:[0,0] op_sel_hi:[0,1]"
      : "=v"(t1) : "v"(cs), "v"(a));
  asm("v_pk_mul_f32 %0, %1, %2 op_sel:[0,0] op_sel_hi:[0,1]"
      : "=v"(t2) : "v"(cs), "v"(b));
  asm("v_pk_fma_f32 %0, %1, %2, %3 op_sel:[1,1,0] op_sel_hi:[1,0,1] neg_hi:[0,1,0]"
      : "=v"(na) : "v"(cs), "v"(b), "v"(t1));
  asm("v_pk_fma_f32 %0, %1, %2, %3 op_sel:[1,1,0] op_sel_hi:[1,0,1] neg_hi:[0,1,0]"
      : "=v"(nb) : "v"(cs), "v"(a), "v"(t2));
  a = na; b = nb;
}

// CRX with per-lane predicate ctrl
template<int MT>
__device__ __forceinline__ void crx_pred(v2f (&v)[16], bool on, v2f cs){
  v2f id = mkv(1.f, 0.f);
  v2f cs_p = on ? cs : id;
  #pragma unroll
  for (int r=0;r<16;r++) if(!(r&MT)) pk_rx(v[r], v[r|MT], cs_p);
}
// CRX ctrl and tgt both register bits
template<int MC,int MT>
__device__ __forceinline__ void crx_rr(v2f (&v)[16], v2f cs){
  #pragma unroll
  for (int r=0;r<16;r++) if((r&MC)&&!(r&MT)) pk_rx(v[r], v[r|MT], cs);
}
// full 1q gate on register bit M
template<int M>
__device__ __forceinline__ void reg_gate(v2f (&v)[16], v2f u00, v2f u01, v2f u10, v2f u11){
  #pragma unroll
  for (int r=0;r<16;r++) if(!(r&M)){
    v2f a = v[r], b = v[r|M];
    v[r]   = pk_cmul_acc(u01, b, pk_cmul(u00, a));
    v[r|M] = pk_cmul_acc(u11, b, pk_cmul(u10, a));
  }
}
// fused matrix F = RX(cs) . W  (column-wise pk_rx) — CRX applied AFTER the 1q gate
__device__ __forceinline__ void build_rxw(v2f cs, v2f w00, v2f w01, v2f w10, v2f w11,
      v2f &f00, v2f &f01, v2f &f10, v2f &f11){
  f00 = w00; f10 = w10; pk_rx(f00, f10, cs);
  f01 = w01; f11 = w11; pk_rx(f01, f11, cs);
}
// fused matrix F = W . RX(cs)  (row-wise pk_rx) — CRX applied BEFORE the 1q gate
__device__ __forceinline__ void build_wrx(v2f cs, v2f w00, v2f w01, v2f w10, v2f w11,
      v2f &f00, v2f &f01, v2f &f10, v2f &f11){
  f00 = w00; f01 = w01; pk_rx(f00, f01, cs);
  f10 = w10; f11 = w11; pk_rx(f10, f11, cs);
}
// 1q gate on M, fused with CRX (post) whose ctrl is register bit MC
template<int MC,int M>
__device__ __forceinline__ void reg_gate_cf(v2f (&v)[16],
      v2f u00, v2f u01, v2f u10, v2f u11, v2f cs){
  v2f f00,f01,f10,f11;
  build_rxw(cs, u00,u01,u10,u11, f00,f01,f10,f11);
  #pragma unroll
  for (int r=0;r<16;r++) if(!(r&M)){
    v2f a = v[r], b = v[r|M];
    if (r & MC){
      v[r]   = pk_cmul_acc(f01, b, pk_cmul(f00, a));
      v[r|M] = pk_cmul_acc(f11, b, pk_cmul(f10, a));
    } else {
      v[r]   = pk_cmul_acc(u01, b, pk_cmul(u00, a));
      v[r|M] = pk_cmul_acc(u11, b, pk_cmul(u10, a));
    }
  }
}
// 1q gate on M, fused with CRX (post) whose ctrl is a per-lane predicate
template<int M>
__device__ __forceinline__ void gate_pred(v2f (&v)[16], bool on, v2f cs,
      v2f u00, v2f u01, v2f u10, v2f u11){
  v2f f00,f01,f10,f11;
  build_rxw(cs, u00,u01,u10,u11, f00,f01,f10,f11);
  v2f g00 = on?f00:u00, g01 = on?f01:u01, g10 = on?f10:u10, g11 = on?f11:u11;
  reg_gate<M>(v, g00,g01,g10,g11);
}
// 1q gate on M, fused with CRX (PRE: CRX before gate) with per-lane predicate ctrl
template<int M>
__device__ __forceinline__ void gate_pred_pre(v2f (&v)[16], bool on, v2f cs,
      v2f u00, v2f u01, v2f u10, v2f u11){
  v2f f00,f01,f10,f11;
  build_wrx(cs, u00,u01,u10,u11, f00,f01,f10,f11);
  v2f g00 = on?f00:u00, g01 = on?f01:u01, g10 = on?f10:u10, g11 = on?f11:u11;
  reg_gate<M>(v, g00,g01,g10,g11);
}

__device__ __forceinline__ int lds_phys(int c){ return c ^ (((c>>4)^(c>>8))&15); }

// Precompute fused U_i^b = Rot_i * RX(x[b,i]) (both layers) + CRX (c,s) pairs
__global__ __launch_bounds__(256) void kprep(const float* __restrict__ x,
      const float* __restrict__ rot1, const float* __restrict__ crx1,
      const float* __restrict__ rot2, const float* __restrict__ crx2,
      v2f* __restrict__ fU, v2f* __restrict__ cm)
{
  int t = blockIdx.x*blockDim.x + threadIdx.x;
  if (t < 2*NBATCH*NQ){
    int w  = t & 15;
    int bb = (t>>4) & (NBATCH-1);
    int L  = t >> 13;
    const float* rot = L ? rot2 : rot1;
    float phi = rot[w*3+0], th = rot[w*3+1], om = rot[w*3+2];
    float ct = cosf(0.5f*th), stt = sinf(0.5f*th);
    float a1 = 0.5f*(phi+om), a2 = 0.5f*(phi-om);
    float emx = cosf(a1), emy = -sinf(a1);
    float epx = cosf(a1), epy =  sinf(a1);
    float edmx = cosf(a2), edmy = -sinf(a2);
    float edpx = cosf(a2), edpy =  sinf(a2);
    float R00x = emx*ct,   R00y = emy*ct;
    float R01x = -edpx*stt, R01y = -edpy*stt;
    float R10x = edmx*stt, R10y = edmy*stt;
    float R11x = epx*ct,   R11y = epy*ct;
    float xv = x[bb*NQ + w];
    float cx = cosf(0.5f*xv), sx = sinf(0.5f*xv);
    v2f* o = fU + (size_t)t*4;
    o[0] = mkv(R00x*cx + R01y*sx,  R00y*cx - R01x*sx);
    o[1] = mkv(R00y*sx + R01x*cx, -R00x*sx + R01y*cx);
    o[2] = mkv(R10x*cx + R11y*sx,  R10y*cx - R11x*sx);
    o[3] = mkv(R10y*sx + R11x*cx, -R10x*sx + R11y*cx);
  }
  if (t < 2*NQ){
    int L = t>>4, w = t&15;
    const float* cxl = L ? crx2 : crx1;
    float thc = cxl[w];
    cm[t] = mkv(cosf(0.5f*thc), sinf(0.5f*thc));
  }
}

// L1-tail table T[b][w11][r]
__global__ __launch_bounds__(256) void kprep2(const v2f* __restrict__ fU,
      const v2f* __restrict__ cm, v2f* __restrict__ Tbl)
{
  int t = blockIdx.x*blockDim.x + threadIdx.x;
  if (t >= 2*NBATCH) return;
  int bb = t >> 1, bit = t & 1;
  const v2f* U = fU + (size_t)bb*64;   // layer-1 gates
  v2f p[16];
  p[0] = U[48]; p[1] = U[50];                       // V12 col0
  p[2] = pk_cmul(p[0], U[54]); p[3] = pk_cmul(p[1], U[54]);
  p[0] = pk_cmul(p[0], U[52]); p[1] = pk_cmul(p[1], U[52]);   // V13
  #pragma unroll
  for (int i=0;i<4;i++){ p[i+4]=pk_cmul(p[i],U[58]); p[i]=pk_cmul(p[i],U[56]); } // V14
  #pragma unroll
  for (int i=0;i<8;i++){ p[i+8]=pk_cmul(p[i],U[62]); p[i]=pk_cmul(p[i],U[60]); } // V15
  // r bits: m1=w12 m2=w13 m4=w14 m8=w15
  if (bit){
    #pragma unroll
    for (int r=0;r<16;r++) if(!(r&1)) pk_rx(p[r], p[r|1], cm[11]);   // CRX(11,12)
  }
  #pragma unroll
  for (int r=0;r<16;r++) if((r&1)&&!(r&2)) pk_rx(p[r], p[r|2], cm[12]); // CRX(12,13)
  #pragma unroll
  for (int r=0;r<16;r++) if((r&2)&&!(r&4)) pk_rx(p[r], p[r|4], cm[13]); // CRX(13,14)
  #pragma unroll
  for (int r=0;r<16;r++) if((r&4)&&!(r&8)) pk_rx(p[r], p[r|8], cm[14]); // CRX(14,15)
  v2f* o = Tbl + ((size_t)bb<<5) + (bit<<4);
  #pragma unroll
  for (int r=0;r<16;r++) o[r] = p[r];
}

// ---------------------------------------------------------------------------
// PASS 1: one block/sample. Product state wires 0..11 + L1 CRX(0,1)..(10,11).
// Stage A: r={1,2,3,4} lane={0,5,6,7,8,9} wv={10,11}
// Stage B: r={5,6,7,8} lane={4,0,1,2,3,9} wv={10,11}
// Stage C: r={9,10,11,8} lane={0,1,2,3,4,5} wv={6,7}
// compact addr bits: [0..5]={11,0,1,2,3,4} [6,7]={5,6} [8..11]={7,8,9,10}
__global__ __launch_bounds__(256) void kpass1(const v2f* __restrict__ fU1,
      const v2f* __restrict__ cm1, f16x2* __restrict__ compact)
{
  int lane = threadIdx.x & 63;
  int wv = threadIdx.x >> 6;
  int bg = blockIdx.x;
  const v2f* U = fU1 + ((size_t)bg<<6);
  v2f a = (lane&1) ? U[2] : U[0];                       // V0
  a = pk_cmul(a, ((lane>>1)&1) ? U[22] : U[20]);        // V5
  a = pk_cmul(a, ((lane>>2)&1) ? U[26] : U[24]);        // V6
  a = pk_cmul(a, ((lane>>3)&1) ? U[30] : U[28]);        // V7
  a = pk_cmul(a, ((lane>>4)&1) ? U[34] : U[32]);        // V8
  a = pk_cmul(a, ((lane>>5)&1) ? U[38] : U[36]);        // V9
  a = pk_cmul(a, (wv&1) ? U[42] : U[40]);               // V10
  a = pk_cmul(a, ((wv>>1)&1) ? U[46] : U[44]);          // V11
  v2f v[16];
  v[0] = pk_cmul(a, U[4]);    v[1] = pk_cmul(a, U[6]);     // V1
  v[2] = pk_cmul(v[0], U[10]); v[3] = pk_cmul(v[1], U[10]);
  v[0] = pk_cmul(v[0], U[8]);  v[1] = pk_cmul(v[1], U[8]); // V2
  #pragma unroll
  for (int i=0;i<4;i++){ v[i+4]=pk_cmul(v[i],U[14]); v[i]=pk_cmul(v[i],U[12]); } // V3
  #pragma unroll
  for (int i=0;i<8;i++){ v[i+8]=pk_cmul(v[i],U[18]); v[i]=pk_cmul(v[i],U[16]); } // V4
  crx_pred<1>(v, (lane&1)!=0, cm1[0]);  // CRX(0,1)
  crx_rr<1,2>(v, cm1[1]);               // CRX(1,2)
  crx_rr<2,4>(v, cm1[2]);               // CRX(2,3)
  crx_rr<4,8>(v, cm1[3]);               // CRX(3,4)
  __shared__ v2f lds[4096];
  // T1: A -> B
  #pragma unroll
  for (int r=0;r<16;r++){
    int c = (lane&1) | (r<<1) | (((lane>>1)&31)<<5) | (wv<<10);
    lds[lds_phys(c)] = v[r];
  }
  __syncthreads();
  #pragma unroll
  for (int r=0;r<16;r++){
    int c = ((lane>>1)&15) | ((lane&1)<<4) | (r<<5) | (((lane>>5)&1)<<9) | (wv<<10);
    v[r] = lds[lds_phys(c)];
  }
  crx_pred<1>(v, (lane&1)!=0, cm1[4]);  // CRX(4,5)
  crx_rr<1,2>(v, cm1[5]);               // CRX(5,6)
  crx_rr<2,4>(v, cm1[6]);               // CRX(6,7)
  crx_rr<4,8>(v, cm1[7]);               // CRX(7,8)
  __syncthreads();
  // T2: B -> C
  #pragma unroll
  for (int r=0;r<16;r++){
    int c = ((lane>>1)&15) | ((lane&1)<<4) | (r<<5) | (((lane>>5)&1)<<9) | (wv<<10);
    lds[lds_phys(c)] = v[r];
  }
  __syncthreads();
  #pragma unroll
  for (int r=0;r<16;r++){
    int c = (lane&63) | (wv<<6) | (((r>>3)&1)<<8) | ((r&7)<<9);
    v[r] = lds[lds_phys(c)];
  }
  crx_rr<8,1>(v, cm1[8]);               // CRX(8,9)
  crx_rr<1,2>(v, cm1[9]);               // CRX(9,10)
  crx_rr<2,4>(v, cm1[10]);              // CRX(10,11)
  __syncthreads();
  // T3: C -> D (write layout)
  #pragma unroll
  for (int r=0;r<16;r++){
    int c = (lane&63) | (wv<<6) | (((r>>3)&1)<<8) | ((r&7)<<9);
    lds[lds_phys(c)] = v[r];
  }
  __syncthreads();
  f16x2* outp = compact + ((size_t)bg<<12);
  #pragma unroll
  for (int r=0;r<16;r++){
    int c = ((lane>>1)&31) | (wv<<5) | (r<<7) | ((lane&1)<<11);
    outp[lane | (wv<<6) | (r<<8)] = pack_h(lds[lds_phys(c)]);
  }
}

// ---------------------------------------------------------------------------
// PASS 2: 16 blocks/sample, h = wires {7,8,9,10}.
// Stage A: r={12,13,14,15} lane={11,0,1,2,3,4} wv={5,6}   (v[r] = a * T[w11][r])
// Stage B: r={0,1,2,3} lane={15,4,5,6,11,12} wv={13,14}
// Stage C: r={4,5,6,15} lane={0,1,11,12,13,3} wv={2,14}
// st addr bits: [0]=w0 [1]=w1 [2]=w11 [3]=w12 [4]=w13 [5]=w3 [6]=w2 [7]=w14
//               [8]=w4 [9]=w5 [10]=w6 [11]=w15 [12..15]=w7..w10
__global__ __launch_bounds__(256) void kpass2(const f16x2* __restrict__ compact,
      const v2f* __restrict__ Tbl, const v2f* __restrict__ fU2,
      const v2f* __restrict__ cm1, const v2f* __restrict__ cm2,
      f16x2* __restrict__ st, int b0)
{
  int lane = threadIdx.x & 63;
  int wv = threadIdx.x >> 6;
  int blk = blockIdx.x;
  int bl = blk >> 4, h = blk & 15;
  int bg = b0 + bl;
  const v2f* U2 = fU2 + ((size_t)bg<<6);
  v2f a = unpack_h(compact[((size_t)bg<<12) | (size_t)(lane | (wv<<6) | (h<<8))]);
  const v2f* T = Tbl + ((size_t)bg<<5) + ((lane&1)<<4);   // w11 = lane bit 0
  v2f v[16];
  #pragma unroll
  for (int r=0;r<16;r++) v[r] = pk_cmul(a, T[r]);
  __shared__ v2f lds[4096];
  // T1: A -> B
  #pragma unroll
  for (int r=0;r<16;r++){
    int c = ((lane>>1)&31) | (wv<<5) | ((lane&1)<<7) | (r<<8);
    lds[lds_phys(c)] = v[r];
  }
  __syncthreads();
  #pragma unroll
  for (int r=0;r<16;r++){
    int c = r | (((lane>>1)&31)<<4) | (wv<<9) | ((lane&1)<<11);
    v[r] = lds[lds_phys(c)];
  }
  // Stage B: r = {w0,w1,w2,w3}; w15 = lane bit 0
  // W0 fused with L1 CRX(15,0): CRX comes BEFORE W0 -> F = W0 . RX
  gate_pred_pre<1>(v, (lane&1)!=0, cm1[15], U2[0], U2[1], U2[2], U2[3]);
  reg_gate_cf<1,2>(v, U2[4], U2[5], U2[6], U2[7],  cm2[0]);  // W1 + CRX(0,1)
  reg_gate_cf<2,4>(v, U2[8], U2[9], U2[10],U2[11], cm2[1]);  // W2 + CRX(1,2)
  reg_gate_cf<4,8>(v, U2[12],U2[13],U2[14],U2[15], cm2[2]);  // W3 + CRX(2,3)
  __syncthreads();
  // T2: B -> C
  #pragma unroll
  for (int r=0;r<16;r++){
    int c = r | (((lane>>1)&31)<<4) | (wv<<9) | ((lane&1)<<11);
    lds[lds_phys(c)] = v[r];
  }
  __syncthreads();
  #pragma unroll
  for (int r=0;r<16;r++){
    int c = (lane&3) | ((wv&1)<<2) | (((lane>>5)&1)<<3) | ((r&7)<<4)
          | (((lane>>2)&7)<<7) | (((wv>>1)&1)<<10) | (((r>>3)&1)<<11);
    v[r] = lds[lds_phys(c)];
  }
  // Stage C: r = {w4,w5,w6,w15}; w3 = lane bit 5
  gate_pred<1>(v, ((lane>>5)&1)!=0, cm2[3], U2[16],U2[17],U2[18],U2[19]); // W4 + CRX(3,4)
  reg_gate_cf<1,2>(v, U2[20],U2[21],U2[22],U2[23], cm2[4]);  // W5 + CRX(4,5)
  reg_gate_cf<2,4>(v, U2[24],U2[25],U2[26],U2[27], cm2[5]);  // W6 + CRX(5,6)
  f16x2* S = st + ((size_t)bl<<16);
  #pragma unroll
  for (int r=0;r<16;r++){
    S[lane | (wv<<6) | (r<<8) | (h<<12)] = pack_h(v[r]);
  }
}

// ---------------------------------------------------------------------------
// PASS 3: 16 blocks/sample, h = wires {2,3,4,5}.
// Stage A: r={7,8,9,10} lane={0,1,11,12,13,14} wv={6,15}
// Stage B: r={11,12,13,14} lane={10,0,1,7,8,9} wv={6,15}
// Stage C: r={15,0,1,6} lane={7,8,9,10,13,14} wv={11,12}
__global__ __launch_bounds__(256) void kpass3(const f16x2* __restrict__ st,
      const v2f* __restrict__ fU2, const v2f* __restrict__ cm2,
      float* __restrict__ expv, int b0)
{
  int lane = threadIdx.x & 63;
  int wv = threadIdx.x >> 6;
  int blk = blockIdx.x;
  int bl = blk >> 4, h = blk & 15;
  int bg = b0 + bl;
  const f16x2* S = st + ((size_t)bl<<16);
  const v2f* U2 = fU2 + ((size_t)bg<<6);
  int abase = (((h>>1)&1)<<5) | ((h&1)<<6) | (((h>>2)&1)<<8) | (((h>>3)&1)<<9)
            | ((wv&1)<<10) | (((wv>>1)&1)<<11);
  v2f v[16];
  #pragma unroll
  for (int r=0;r<16;r++){
    v[r] = unpack_h(S[(lane&31) | (((lane>>5)&1)<<7) | abase | (r<<12)]);
  }
  // Stage A: r = {w7,w8,w9,w10}; w6 = wv bit 0 (wave-uniform)
  {
    v2f g00=U2[28], g01=U2[29], g10=U2[30], g11=U2[31];
    if (wv & 1){ pk_rx(g00, g10, cm2[6]); pk_rx(g01, g11, cm2[6]); }
    reg_gate<1>(v, g00,g01,g10,g11);                         // W7 + CRX(6,7)
  }
  reg_gate_cf<1,2>(v, U2[32],U2[33],U2[34],U2[35], cm2[7]);  // W8 + CRX(7,8)
  reg_gate_cf<2,4>(v, U2[36],U2[37],U2[38],U2[39], cm2[8]);  // W9 + CRX(8,9)
  reg_gate_cf<4,8>(v, U2[40],U2[41],U2[42],U2[43], cm2[9]);  // W10 + CRX(9,10)
  __shared__ v2f lds[4096];
  // T1: A -> B
  #pragma unroll
  for (int r=0;r<16;r++){
    int c = (lane&3) | ((wv&1)<<2) | (r<<3) | (((lane>>2)&15)<<7) | (((wv>>1)&1)<<11);
    lds[lds_phys(c)] = v[r];
  }
  __syncthreads();
  #pragma unroll
  for (int r=0;r<16;r++){
    int c = ((lane>>1)&3) | ((wv&1)<<2) | (((lane>>3)&7)<<3) | ((lane&1)<<6)
          | (r<<7) | (((wv>>1)&1)<<11);
    v[r] = lds[lds_phys(c)];
  }
  // Stage B: r = {w11,w12,w13,w14}; w10 = lane bit 0
  gate_pred<1>(v, (lane&1)!=0, cm2[10], U2[44],U2[45],U2[46],U2[47]); // W11 + CRX(10,11)
  reg_gate_cf<1,2>(v, U2[48],U2[49],U2[50],U2[51], cm2[11]); // W12 + CRX(11,12)
  reg_gate_cf<2,4>(v, U2[52],U2[53],U2[54],U2[55], cm2[12]); // W13 + CRX(12,13)
  reg_gate_cf<4,8>(v, U2[56],U2[57],U2[58],U2[59], cm2[13]); // W14 + CRX(13,14)
  __syncthreads();
  // T2: B -> C
  #pragma unroll
  for (int r=0;r<16;r++){
    int c = ((lane>>1)&3) | ((wv&1)<<2) | (((lane>>3)&7)<<3) | ((lane&1)<<6)
          | (r<<7) | (((wv>>1)&1)<<11);
    lds[lds_phys(c)] = v[r];
  }
  __syncthreads();
  #pragma unroll
  for (int r=0;r<16;r++){
    int c = ((r>>1)&7) | ((lane&15)<<3) | ((wv&3)<<7) | (((lane>>4)&3)<<9) | ((r&1)<<11);
    v[r] = lds[lds_phys(c)];
  }
  // Stage C: r = {w15,w0,w1,w6}; w14 = lane bit 5
  gate_pred<1>(v, ((lane>>5)&1)!=0, cm2[14], U2[60],U2[61],U2[62],U2[63]); // W15 + CRX(14,15)
  crx_rr<1,2>(v, cm2[15]);              // CRX(15,0)
  // expvals. regs: w15=m1 w0=m2 w1=m4 w6=m8; lanes l0..l5={7,8,9,10,13,14}; wv={11,12}; h={2,3,4,5}
  float tot=0.f, S0=0.f, S1=0.f, S2=0.f, S3=0.f;
  #pragma unroll
  for (int r=0;r<16;r++){
    float p = v[r].x*v[r].x + v[r].y*v[r].y;
    tot += p;
    if (r&1) S0+=p;
    if (r&2) S1+=p;
    if (r&4) S2+=p;
    if (r&8) S3+=p;
  }
  float s = tot;
  float u[6];
  #pragma unroll
  for (int b=0;b<6;b++){
    int m = 1<<b;
    float t = __shfl_xor(s, m, 64);
    u[b] = s - t;
    s = s + t;
    #pragma unroll
    for (int j=0;j<6;j++) if (j<b) u[j] += __shfl_xor(u[j], m, 64);
  }
  #pragma unroll
  for (int d=1; d<64; d<<=1){
    S0 += __shfl_xor(S0, d, 64);
    S1 += __shfl_xor(S1, d, 64);
    S2 += __shfl_xor(S2, d, 64);
    S3 += __shfl_xor(S3, d, 64);
  }
  __syncthreads();
  float* ef = (float*)lds;
  if (lane==0){
    ef[wv*16+15]=s-2.f*S0; ef[wv*16+0]=s-2.f*S1; ef[wv*16+1]=s-2.f*S2; ef[wv*16+6]=s-2.f*S3;
    ef[wv*16+7]=u[0]; ef[wv*16+8]=u[1]; ef[wv*16+9]=u[2]; ef[wv*16+10]=u[3];
    ef[wv*16+13]=u[4]; ef[wv*16+14]=u[5];
    ef[wv*16+11]=(wv&1)?-s:s; ef[wv*16+12]=(wv&2)?-s:s;
    ef[wv*16+2]=(h&1)?-s:s; ef[wv*16+3]=(h&2)?-s:s; ef[wv*16+4]=(h&4)?-s:s; ef[wv*16+5]=(h&8)?-s:s;
  }
  __syncthreads();
  if (threadIdx.x < 16){
    float r4 = ef[threadIdx.x]+ef[16+threadIdx.x]+ef[32+threadIdx.x]+ef[48+threadIdx.x];
    atomicAdd(expv + (size_t)bg*NQ + threadIdx.x, r4);
  }
}

__global__ __launch_bounds__(128) void klogits(const float* __restrict__ expv,
      const float* __restrict__ W, const float* __restrict__ bias,
      float* __restrict__ out)
{
  int b = blockIdx.x;
  int tid = threadIdx.x;
  __shared__ float f[NQ];
  __shared__ float lg[NCLS];
  if (tid < NQ) f[tid] = expv[b*NQ + tid];
  __syncthreads();
  if (tid < NCLS){
    float acc = bias[tid];
    #pragma unroll
    for (int i=0;i<NQ;i++) acc += f[i]*W[tid*NQ+i];
    lg[tid] = acc;
  }
  __syncthreads();
  if (tid < NCLS){
    float m = -1e30f;
    for (int i=0;i<NCLS;i++) m = fmaxf(m, lg[i]);
    float sum = 0.f;
    for (int i=0;i<NCLS;i++) sum += expf(lg[i]-m);
    out[b*NCLS+tid] = lg[tid] - m - logf(sum);
  }
}

extern "C" void kernel_launch(void* const* d_in, const int* in_sizes, int n_in,
                              void* d_out, int out_size, void* d_ws, size_t ws_size,
                              hipStream_t stream)
{
  const float* x    = (const float*)d_in[0];
  const float* rot1 = (const float*)d_in[1];
  const float* crx1 = (const float*)d_in[2];
  const float* rot2 = (const float*)d_in[3];
  const float* crx2 = (const float*)d_in[4];
  const float* W    = (const float*)d_in[5];
  const float* bias = (const float*)d_in[6];
  float* out = (float*)d_out;

  char* ws = (char*)d_ws;
  float* expv = (float*)ws;                        // 32 KB @ 0
  v2f*   fU   = (v2f*)(ws + (40<<10));             // 512 KB @ 40K
  v2f*   cmm  = (v2f*)(ws + (560<<10));            // 256 B  @ 560K
  v2f*   Tbl  = (v2f*)(ws + (564<<10));            // 128 KB @ 564K
  f16x2* compact = (f16x2*)(ws + (704<<10));       // 8 MB   @ 704K
  const size_t stOff = (size_t)(704<<10) + ((size_t)NBATCH<<14);
  f16x2* st   = (f16x2*)(ws + stOff);

  hipMemsetAsync(expv, 0, NBATCH*NQ*sizeof(float), stream);
  kprep<<<(2*NBATCH*NQ + 255)/256, 256, 0, stream>>>(x, rot1, crx1, rot2, crx2, fU, cmm);

  v2f* fU1 = fU;
  v2f* fU2 = fU + 32768;
  v2f* cm1 = cmm;
  v2f* cm2 = cmm + 16;

  kprep2<<<(2*NBATCH + 255)/256, 256, 0, stream>>>(fU1, cm1, Tbl);
  kpass1<<<NBATCH, 256, 0, stream>>>(fU1, cm1, compact);

  size_t avail = (ws_size > stOff) ? (ws_size - stOff) : 0;
  int chunk = NBATCH;
  while (chunk > 1 && (size_t)chunk*65536*sizeof(f16x2) > avail) chunk >>= 1;

  for (int b0 = 0; b0 < NBATCH; b0 += chunk){
    kpass2<<<chunk*16, 256, 0, stream>>>(compact, Tbl, fU2, cm1, cm2, st, b0);
    kpass3<<<chunk*16, 256, 0, stream>>>(st, fU2, cm2, expv, b0);
  }
  klogits<<<NBATCH, 128, 0, stream>>>(expv, W, bias, out);
}

// Round 9
// 137.945 us; speedup vs baseline: 3.6825x; 1.2466x over previous
//
#include <hip/hip_runtime.h>
#include <math.h>

#define NQ 16
#define NBATCH 512
#define NCLS 100

typedef float v2f __attribute__((ext_vector_type(2)));
typedef __fp16 f16x2 __attribute__((ext_vector_type(2)));
typedef _Float16 half8 __attribute__((ext_vector_type(8)));
typedef float f32x4 __attribute__((ext_vector_type(4)));

__device__ __forceinline__ v2f mkv(float x, float y){ v2f r; r.x = x; r.y = y; return r; }
__device__ __forceinline__ f16x2 pack_h(v2f a){ return __builtin_amdgcn_cvt_pkrtz(a.x, a.y); }
__device__ __forceinline__ f16x2 pack_h2(float a, float b){ return __builtin_amdgcn_cvt_pkrtz(a, b); }
__device__ __forceinline__ v2f unpack_h(f16x2 h){ return mkv((float)h.x, (float)h.y); }

union pack16 { f16x2 h[4]; uint4 u; };

// ---- packed-f32 complex primitives (VOP3P v_pk_*) ----
__device__ __forceinline__ v2f pk_cmul(v2f a, v2f b){
  v2f t, d;
  asm("v_pk_mul_f32 %0, %1, %2 op_sel:[0,0] op_sel_hi:[1,0]"
      : "=v"(t) : "v"(a), "v"(b));
  asm("v_pk_fma_f32 %0, %1, %2, %3 op_sel:[1,1,0] op_sel_hi:[0,1,1] neg_lo:[1,0,0]"
      : "=v"(d) : "v"(a), "v"(b), "v"(t));
  return d;
}
__device__ __forceinline__ v2f pk_cmul_acc(v2f a, v2f b, v2f acc){
  v2f t, d;
  asm("v_pk_fma_f32 %0, %1, %2, %3 op_sel:[0,0,0] op_sel_hi:[1,0,1]"
      : "=v"(t) : "v"(a), "v"(b), "v"(acc));
  asm("v_pk_fma_f32 %0, %1, %2, %3 op_sel:[1,1,0] op_sel_hi:[0,1,1] neg_lo:[1,0,0]"
      : "=v"(d) : "v"(a), "v"(b), "v"(t));
  return d;
}
// RX pair rotation with cs=(c,s)
__device__ __forceinline__ void pk_rx(v2f &a, v2f &b, v2f cs){
  v2f t1, t2, na, nb;
  asm("v_pk_mul_f32 %0, %1, %2 op_sel:[0,0] op_sel_hi:[0,1]"
      : "=v"(t1) : "v"(cs), "v"(a));
  asm("v_pk_mul_f32 %0, %1, %2 op_sel:[0,0] op_sel_hi:[0,1]"
      : "=v"(t2) : "v"(cs), "v"(b));
  asm("v_pk_fma_f32 %0, %1, %2, %3 op_sel:[1,1,0] op_sel_hi:[1,0,1] neg_hi:[0,1,0]"
      : "=v"(na) : "v"(cs), "v"(b), "v"(t1));
  asm("v_pk_fma_f32 %0, %1, %2, %3 op_sel:[1,1,0] op_sel_hi:[1,0,1] neg_hi:[0,1,0]"
      : "=v"(nb) : "v"(cs), "v"(a), "v"(t2));
  a = na; b = nb;
}

// CRX with per-lane predicate ctrl
template<int MT>
__device__ __forceinline__ void crx_pred(v2f (&v)[16], bool on, v2f cs){
  v2f id = mkv(1.f, 0.f);
  v2f cs_p = on ? cs : id;
  #pragma unroll
  for (int r=0;r<16;r++) if(!(r&MT)) pk_rx(v[r], v[r|MT], cs_p);
}
// CRX applied unconditionally
template<int MT>
__device__ __forceinline__ void crx_on(v2f (&v)[16], v2f cs){
  #pragma unroll
  for (int r=0;r<16;r++) if(!(r&MT)) pk_rx(v[r], v[r|MT], cs);
}
// CRX ctrl and tgt both register bits
template<int MC,int MT>
__device__ __forceinline__ void crx_rr(v2f (&v)[16], v2f cs){
  #pragma unroll
  for (int r=0;r<16;r++) if((r&MC)&&!(r&MT)) pk_rx(v[r], v[r|MT], cs);
}
// full 1q gate on register bit M
template<int M>
__device__ __forceinline__ void reg_gate(v2f (&v)[16], v2f u00, v2f u01, v2f u10, v2f u11){
  #pragma unroll
  for (int r=0;r<16;r++) if(!(r&M)){
    v2f a = v[r], b = v[r|M];
    v[r]   = pk_cmul_acc(u01, b, pk_cmul(u00, a));
    v[r|M] = pk_cmul_acc(u11, b, pk_cmul(u10, a));
  }
}
// F = RX(cs) . W  (CRX after gate)
__device__ __forceinline__ void build_rxw(v2f cs, v2f w00, v2f w01, v2f w10, v2f w11,
      v2f &f00, v2f &f01, v2f &f10, v2f &f11){
  f00 = w00; f10 = w10; pk_rx(f00, f10, cs);
  f01 = w01; f11 = w11; pk_rx(f01, f11, cs);
}
// F = W . RX(cs)  (CRX before gate)
__device__ __forceinline__ void build_wrx(v2f cs, v2f w00, v2f w01, v2f w10, v2f w11,
      v2f &f00, v2f &f01, v2f &f10, v2f &f11){
  f00 = w00; f01 = w01; pk_rx(f00, f01, cs);
  f10 = w10; f11 = w11; pk_rx(f10, f11, cs);
}
template<int MC,int M>
__device__ __forceinline__ void reg_gate_cf(v2f (&v)[16],
      v2f u00, v2f u01, v2f u10, v2f u11, v2f cs){
  v2f f00,f01,f10,f11;
  build_rxw(cs, u00,u01,u10,u11, f00,f01,f10,f11);
  #pragma unroll
  for (int r=0;r<16;r++) if(!(r&M)){
    v2f a = v[r], b = v[r|M];
    if (r & MC){
      v[r]   = pk_cmul_acc(f01, b, pk_cmul(f00, a));
      v[r|M] = pk_cmul_acc(f11, b, pk_cmul(f10, a));
    } else {
      v[r]   = pk_cmul_acc(u01, b, pk_cmul(u00, a));
      v[r|M] = pk_cmul_acc(u11, b, pk_cmul(u10, a));
    }
  }
}
template<int M>
__device__ __forceinline__ void gate_pred(v2f (&v)[16], bool on, v2f cs,
      v2f u00, v2f u01, v2f u10, v2f u11){
  v2f f00,f01,f10,f11;
  build_rxw(cs, u00,u01,u10,u11, f00,f01,f10,f11);
  v2f g00 = on?f00:u00, g01 = on?f01:u01, g10 = on?f10:u10, g11 = on?f11:u11;
  reg_gate<M>(v, g00,g01,g10,g11);
}
template<int M>
__device__ __forceinline__ void gate_pred_pre(v2f (&v)[16], bool on, v2f cs,
      v2f u00, v2f u01, v2f u10, v2f u11){
  v2f f00,f01,f10,f11;
  build_wrx(cs, u00,u01,u10,u11, f00,f01,f10,f11);
  v2f g00 = on?f00:u00, g01 = on?f01:u01, g10 = on?f10:u10, g11 = on?f11:u11;
  reg_gate<M>(v, g00,g01,g10,g11);
}

__device__ __forceinline__ int lds_phys(int c){ return c ^ (((c>>4)^(c>>8))&15); }
// 16B-chunk swizzled address (uint4 units) for canonical LDS layout [m(8b)][r(4b)]
__device__ __forceinline__ int swz(int m, int q){
  return m*4 + (q ^ (m&3) ^ ((m>>2)&3));
}

// Precompute fused U_i^b = Rot_i * RX(x[b,i]) (both layers) + CRX (c,s) pairs
__global__ __launch_bounds__(256) void kprep(const float* __restrict__ x,
      const float* __restrict__ rot1, const float* __restrict__ crx1,
      const float* __restrict__ rot2, const float* __restrict__ crx2,
      v2f* __restrict__ fU, v2f* __restrict__ cm)
{
  int t = blockIdx.x*blockDim.x + threadIdx.x;
  if (t < 2*NBATCH*NQ){
    int w  = t & 15;
    int bb = (t>>4) & (NBATCH-1);
    int L  = t >> 13;
    const float* rot = L ? rot2 : rot1;
    float phi = rot[w*3+0], th = rot[w*3+1], om = rot[w*3+2];
    float ct = cosf(0.5f*th), stt = sinf(0.5f*th);
    float a1 = 0.5f*(phi+om), a2 = 0.5f*(phi-om);
    float emx = cosf(a1), emy = -sinf(a1);
    float epx = cosf(a1), epy =  sinf(a1);
    float edmx = cosf(a2), edmy = -sinf(a2);
    float edpx = cosf(a2), edpy =  sinf(a2);
    float R00x = emx*ct,   R00y = emy*ct;
    float R01x = -edpx*stt, R01y = -edpy*stt;
    float R10x = edmx*stt, R10y = edmy*stt;
    float R11x = epx*ct,   R11y = epy*ct;
    float xv = x[bb*NQ + w];
    float cx = cosf(0.5f*xv), sx = sinf(0.5f*xv);
    v2f* o = fU + (size_t)t*4;
    o[0] = mkv(R00x*cx + R01y*sx,  R00y*cx - R01x*sx);
    o[1] = mkv(R00y*sx + R01x*cx, -R00x*sx + R01y*cx);
    o[2] = mkv(R10x*cx + R11y*sx,  R10y*cx - R11x*sx);
    o[3] = mkv(R10y*sx + R11x*cx, -R10x*sx + R11y*cx);
  }
  if (t < 2*NQ){
    int L = t>>4, w = t&15;
    const float* cxl = L ? crx2 : crx1;
    float thc = cxl[w];
    cm[t] = mkv(cosf(0.5f*thc), sinf(0.5f*thc));
  }
}

// L1-tail table T[b][w11][r]
__global__ __launch_bounds__(256) void kprep2(const v2f* __restrict__ fU,
      const v2f* __restrict__ cm, v2f* __restrict__ Tbl)
{
  int t = blockIdx.x*blockDim.x + threadIdx.x;
  if (t >= 2*NBATCH) return;
  int bb = t >> 1, bit = t & 1;
  const v2f* U = fU + (size_t)bb*64;
  v2f p[16];
  p[0] = U[48]; p[1] = U[50];
  p[2] = pk_cmul(p[0], U[54]); p[3] = pk_cmul(p[1], U[54]);
  p[0] = pk_cmul(p[0], U[52]); p[1] = pk_cmul(p[1], U[52]);
  #pragma unroll
  for (int i=0;i<4;i++){ p[i+4]=pk_cmul(p[i],U[58]); p[i]=pk_cmul(p[i],U[56]); }
  #pragma unroll
  for (int i=0;i<8;i++){ p[i+8]=pk_cmul(p[i],U[62]); p[i]=pk_cmul(p[i],U[60]); }
  if (bit){
    #pragma unroll
    for (int r=0;r<16;r++) if(!(r&1)) pk_rx(p[r], p[r|1], cm[11]);
  }
  #pragma unroll
  for (int r=0;r<16;r++) if((r&1)&&!(r&2)) pk_rx(p[r], p[r|2], cm[12]);
  #pragma unroll
  for (int r=0;r<16;r++) if((r&2)&&!(r&4)) pk_rx(p[r], p[r|4], cm[13]);
  #pragma unroll
  for (int r=0;r<16;r++) if((r&4)&&!(r&8)) pk_rx(p[r], p[r|8], cm[14]);
  v2f* o = Tbl + ((size_t)bb<<5) + (bit<<4);
  #pragma unroll
  for (int r=0;r<16;r++) o[r] = p[r];
}

// ---------------------------------------------------------------------------
// kprepG: per (sample, stage, variant, col): build the 16x16 complex stage
// matrix G, store MFMA B fragments (B1 for D_re, B2 for D_im).
// Table is 512*2*2*2 = 4096 rows of 64 lanes x 8 halves = 4 MB.
__global__ __launch_bounds__(256) void kprepG(const v2f* __restrict__ fU2,
      const v2f* __restrict__ cm2, _Float16* __restrict__ Bt16)
{
  int t = blockIdx.x*blockDim.x + threadIdx.x;
  if (t >= NBATCH*2*2*16) return;
  int r0 = t & 15;
  int var = (t>>4) & 1;
  int stage = (t>>5) & 1;
  int bg = t >> 6;
  const v2f* U2 = fU2 + ((size_t)bg<<6);
  v2f v[16];
  #pragma unroll
  for (int r=0;r<16;r++) v[r] = mkv(0.f,0.f);
  v[r0] = mkv(1.f,0.f);
  if (stage == 0){
    reg_gate<1>(v, U2[28],U2[29],U2[30],U2[31]);   // W7
    reg_gate<2>(v, U2[32],U2[33],U2[34],U2[35]);   // W8
    reg_gate<4>(v, U2[36],U2[37],U2[38],U2[39]);   // W9
    reg_gate<8>(v, U2[40],U2[41],U2[42],U2[43]);   // W10
    if (var) crx_on<1>(v, cm2[6]);                 // CRX(6,7)
    crx_rr<1,2>(v, cm2[7]);                        // CRX(7,8)
    crx_rr<2,4>(v, cm2[8]);                        // CRX(8,9)
    crx_rr<4,8>(v, cm2[9]);                        // CRX(9,10)
  } else {
    reg_gate<1>(v, U2[44],U2[45],U2[46],U2[47]);   // W11
    reg_gate<2>(v, U2[48],U2[49],U2[50],U2[51]);   // W12
    reg_gate<4>(v, U2[52],U2[53],U2[54],U2[55]);   // W13
    reg_gate<8>(v, U2[56],U2[57],U2[58],U2[59]);   // W14
    if (var) crx_on<1>(v, cm2[10]);                // CRX(10,11)
    crx_rr<1,2>(v, cm2[11]);                       // CRX(11,12)
    crx_rr<2,4>(v, cm2[12]);                       // CRX(12,13)
    crx_rr<4,8>(v, cm2[13]);                       // CRX(13,14)
  }
  size_t hb = (((size_t)bg*2 + stage)*2 + var)*2;
  int k0 = 2*r0;
  int lk = 16*(k0>>3);
  int j0 = k0 & 7;
  #pragma unroll
  for (int n=0;n<16;n++){
    _Float16 re  = (_Float16)v[n].x;
    _Float16 im  = (_Float16)v[n].y;
    _Float16 nim = (_Float16)(-v[n].y);
    size_t ln = (size_t)(lk + n);
    Bt16[((hb+0)*64 + ln)*8 + j0]   = re;
    Bt16[((hb+0)*64 + ln)*8 + j0+1] = nim;
    Bt16[((hb+1)*64 + ln)*8 + j0]   = im;
    Bt16[((hb+1)*64 + ln)*8 + j0+1] = re;
  }
}

// ---------------------------------------------------------------------------
// PASS 1: unchanged (R7)
__global__ __launch_bounds__(256) void kpass1(const v2f* __restrict__ fU1,
      const v2f* __restrict__ cm1, f16x2* __restrict__ compact)
{
  int lane = threadIdx.x & 63;
  int wv = threadIdx.x >> 6;
  int bg = blockIdx.x;
  const v2f* U = fU1 + ((size_t)bg<<6);
  v2f a = (lane&1) ? U[2] : U[0];
  a = pk_cmul(a, ((lane>>1)&1) ? U[22] : U[20]);
  a = pk_cmul(a, ((lane>>2)&1) ? U[26] : U[24]);
  a = pk_cmul(a, ((lane>>3)&1) ? U[30] : U[28]);
  a = pk_cmul(a, ((lane>>4)&1) ? U[34] : U[32]);
  a = pk_cmul(a, ((lane>>5)&1) ? U[38] : U[36]);
  a = pk_cmul(a, (wv&1) ? U[42] : U[40]);
  a = pk_cmul(a, ((wv>>1)&1) ? U[46] : U[44]);
  v2f v[16];
  v[0] = pk_cmul(a, U[4]);    v[1] = pk_cmul(a, U[6]);
  v[2] = pk_cmul(v[0], U[10]); v[3] = pk_cmul(v[1], U[10]);
  v[0] = pk_cmul(v[0], U[8]);  v[1] = pk_cmul(v[1], U[8]);
  #pragma unroll
  for (int i=0;i<4;i++){ v[i+4]=pk_cmul(v[i],U[14]); v[i]=pk_cmul(v[i],U[12]); }
  #pragma unroll
  for (int i=0;i<8;i++){ v[i+8]=pk_cmul(v[i],U[18]); v[i]=pk_cmul(v[i],U[16]); }
  crx_pred<1>(v, (lane&1)!=0, cm1[0]);
  crx_rr<1,2>(v, cm1[1]);
  crx_rr<2,4>(v, cm1[2]);
  crx_rr<4,8>(v, cm1[3]);
  __shared__ v2f lds[4096];
  #pragma unroll
  for (int r=0;r<16;r++){
    int c = (lane&1) | (r<<1) | (((lane>>1)&31)<<5) | (wv<<10);
    lds[lds_phys(c)] = v[r];
  }
  __syncthreads();
  #pragma unroll
  for (int r=0;r<16;r++){
    int c = ((lane>>1)&15) | ((lane&1)<<4) | (r<<5) | (((lane>>5)&1)<<9) | (wv<<10);
    v[r] = lds[lds_phys(c)];
  }
  crx_pred<1>(v, (lane&1)!=0, cm1[4]);
  crx_rr<1,2>(v, cm1[5]);
  crx_rr<2,4>(v, cm1[6]);
  crx_rr<4,8>(v, cm1[7]);
  __syncthreads();
  #pragma unroll
  for (int r=0;r<16;r++){
    int c = ((lane>>1)&15) | ((lane&1)<<4) | (r<<5) | (((lane>>5)&1)<<9) | (wv<<10);
    lds[lds_phys(c)] = v[r];
  }
  __syncthreads();
  #pragma unroll
  for (int r=0;r<16;r++){
    int c = (lane&63) | (wv<<6) | (((r>>3)&1)<<8) | ((r&7)<<9);
    v[r] = lds[lds_phys(c)];
  }
  crx_rr<8,1>(v, cm1[8]);
  crx_rr<1,2>(v, cm1[9]);
  crx_rr<2,4>(v, cm1[10]);
  __syncthreads();
  #pragma unroll
  for (int r=0;r<16;r++){
    int c = (lane&63) | (wv<<6) | (((r>>3)&1)<<8) | ((r&7)<<9);
    lds[lds_phys(c)] = v[r];
  }
  __syncthreads();
  f16x2* outp = compact + ((size_t)bg<<12);
  #pragma unroll
  for (int r=0;r<16;r++){
    int c = ((lane>>1)&31) | (wv<<5) | (r<<7) | ((lane&1)<<11);
    outp[lane | (wv<<6) | (r<<8)] = pack_h(lds[lds_phys(c)]);
  }
}

// ---------------------------------------------------------------------------
// PASS 2: unchanged (R7)
__global__ __launch_bounds__(256) void kpass2(const f16x2* __restrict__ compact,
      const v2f* __restrict__ Tbl, const v2f* __restrict__ fU2,
      const v2f* __restrict__ cm1, const v2f* __restrict__ cm2,
      f16x2* __restrict__ st, int b0)
{
  int lane = threadIdx.x & 63;
  int wv = threadIdx.x >> 6;
  int blk = blockIdx.x;
  int bl = blk >> 4, h = blk & 15;
  int bg = b0 + bl;
  const v2f* U2 = fU2 + ((size_t)bg<<6);
  v2f a = unpack_h(compact[((size_t)bg<<12) | (size_t)(lane | (wv<<6) | (h<<8))]);
  const v2f* T = Tbl + ((size_t)bg<<5) + ((lane&1)<<4);
  v2f v[16];
  #pragma unroll
  for (int r=0;r<16;r++) v[r] = pk_cmul(a, T[r]);
  __shared__ v2f lds[4096];
  #pragma unroll
  for (int r=0;r<16;r++){
    int c = ((lane>>1)&31) | (wv<<5) | ((lane&1)<<7) | (r<<8);
    lds[lds_phys(c)] = v[r];
  }
  __syncthreads();
  #pragma unroll
  for (int r=0;r<16;r++){
    int c = r | (((lane>>1)&31)<<4) | (wv<<9) | ((lane&1)<<11);
    v[r] = lds[lds_phys(c)];
  }
  gate_pred_pre<1>(v, (lane&1)!=0, cm1[15], U2[0], U2[1], U2[2], U2[3]);
  reg_gate_cf<1,2>(v, U2[4], U2[5], U2[6], U2[7],  cm2[0]);
  reg_gate_cf<2,4>(v, U2[8], U2[9], U2[10],U2[11], cm2[1]);
  reg_gate_cf<4,8>(v, U2[12],U2[13],U2[14],U2[15], cm2[2]);
  __syncthreads();
  #pragma unroll
  for (int r=0;r<16;r++){
    int c = r | (((lane>>1)&31)<<4) | (wv<<9) | ((lane&1)<<11);
    lds[lds_phys(c)] = v[r];
  }
  __syncthreads();
  #pragma unroll
  for (int r=0;r<16;r++){
    int c = (lane&3) | ((wv&1)<<2) | (((lane>>5)&1)<<3) | ((r&7)<<4)
          | (((lane>>2)&7)<<7) | (((wv>>1)&1)<<10) | (((r>>3)&1)<<11);
    v[r] = lds[lds_phys(c)];
  }
  gate_pred<1>(v, ((lane>>5)&1)!=0, cm2[3], U2[16],U2[17],U2[18],U2[19]);
  reg_gate_cf<1,2>(v, U2[20],U2[21],U2[22],U2[23], cm2[4]);
  reg_gate_cf<2,4>(v, U2[24],U2[25],U2[26],U2[27], cm2[5]);
  f16x2* S = st + ((size_t)bl<<16);
  #pragma unroll
  for (int r=0;r<16;r++){
    S[lane | (wv<<6) | (r<<8) | (h<<12)] = pack_h(v[r]);
  }
}

// ---------------------------------------------------------------------------
// PASS 3 (MFMA): h = wires {2,3,4,5}.
// Thread wires at load: l0=w0 l1=w1 l2=w11 l3=w12 l4=w13 l5=w14, wv0=w6, wv1=w15,
// per-reg r = (w7,w8,w9,w10).
// canonical1 m-bits: b0..3=w11,w12,w13,w14  b4=w15 b5=w0 b6=w6(wave) b7=w1
// canonical2 m-bits: b0=w15 b1=w0 b2=w7 b3=w8 b4=w9 b5=w1 b6=w10(wave) b7=w6
__global__ __launch_bounds__(256) void kpass3(const f16x2* __restrict__ st,
      const v2f* __restrict__ fU2, const v2f* __restrict__ cm2,
      const half8* __restrict__ Btab,
      float* __restrict__ expv, int b0)
{
  int lane = threadIdx.x & 63;
  int wv = threadIdx.x >> 6;
  int blk = blockIdx.x;
  int bl = blk >> 4, h = blk & 15;
  int bg = b0 + bl;
  const f16x2* S = st + ((size_t)bl<<16);
  const v2f* U2 = fU2 + ((size_t)bg<<6);
  __shared__ uint4 lbufA[1024];
  __shared__ uint4 lbufB[1024];

  int abase = (((h>>1)&1)<<5) | ((h&1)<<6) | (((h>>2)&1)<<8) | (((h>>3)&1)<<9)
            | ((wv&1)<<10) | (((wv>>1)&1)<<11);
  f16x2 v[16];
  #pragma unroll
  for (int r=0;r<16;r++){
    v[r] = S[(lane&31) | (((lane>>5)&1)<<7) | abase | (r<<12)];
  }
  int m1 = ((lane>>2)&15) | (((wv>>1)&1)<<4) | ((lane&1)<<5)
         | ((wv&1)<<6) | (((lane>>1)&1)<<7);
  #pragma unroll
  for (int q=0;q<4;q++){
    pack16 pk;
    pk.h[0]=v[4*q]; pk.h[1]=v[4*q+1]; pk.h[2]=v[4*q+2]; pk.h[3]=v[4*q+3];
    lbufA[swz(m1,q)] = pk.u;
  }

  int sel = wv & 1;     // w6 for stage1, w10 for stage2
  size_t hb1 = (((size_t)bg*2 + 0)*2 + sel)*2;
  size_t hb2 = (((size_t)bg*2 + 1)*2 + sel)*2;
  half8 B1a = Btab[(hb1+0)*64 + lane];
  half8 B2a = Btab[(hb1+1)*64 + lane];
  half8 B1b = Btab[(hb2+0)*64 + lane];
  half8 B2b = Btab[(hb2+1)*64 + lane];
  f32x4 zz = {0.f, 0.f, 0.f, 0.f};

  __syncthreads();

  // ---- stage 1: G1 MFMA, write canonical2 ----
  {
    int n = lane & 15;
    int q2 = lane >> 4;
    #pragma unroll
    for (int t=0;t<4;t++){
      int m = (wv<<6) | (t<<4) | (lane&15);
      half8 af = *(const half8*)&lbufA[swz(m, lane>>4)];
      f32x4 dre = __builtin_amdgcn_mfma_f32_16x16x32_f16(af, B1a, zz, 0, 0, 0);
      f32x4 dim = __builtin_amdgcn_mfma_f32_16x16x32_f16(af, B2a, zz, 0, 0, 0);
      int m2 = t | ((n&7)<<2) | (((wv>>1)&1)<<5) | (((n>>3)&1)<<6) | ((wv&1)<<7);
      pack16 pk;
      #pragma unroll
      for (int rg=0;rg<4;rg++) pk.h[rg] = pack_h2(dre[rg], dim[rg]);
      lbufB[swz(m2, q2)] = pk.u;
    }
  }
  __syncthreads();

  // ---- stage 2: G2 MFMA + VALU tail + expval ----
  v2f G00, G01, G10, G11;
  {
    v2f g00=U2[60], g01=U2[61], g10=U2[62], g11=U2[63];
    v2f f00,f01,f10,f11;
    build_rxw(cm2[14], g00,g01,g10,g11, f00,f01,f10,f11);
    bool on3 = ((lane>>3)&1) != 0;   // w14 = lane bit 3 (col n bit 3)
    G00 = on3?f00:g00; G01 = on3?f01:g01; G10 = on3?f10:g10; G11 = on3?f11:g11;
  }
  float tot=0.f, S15=0.f, S0w=0.f, S9=0.f, S1w=0.f;
  #pragma unroll
  for (int t2=0;t2<4;t2++){
    int m = (wv<<6) | (t2<<4) | (lane&15);
    half8 af = *(const half8*)&lbufB[swz(m, lane>>4)];
    f32x4 ere = __builtin_amdgcn_mfma_f32_16x16x32_f16(af, B1b, zz, 0, 0, 0);
    f32x4 eim = __builtin_amdgcn_mfma_f32_16x16x32_f16(af, B2b, zz, 0, 0, 0);
    v2f a0 = mkv(ere[0], eim[0]);
    v2f a1 = mkv(ere[1], eim[1]);
    v2f a2 = mkv(ere[2], eim[2]);
    v2f a3 = mkv(ere[3], eim[3]);
    v2f n0 = pk_cmul_acc(G01, a1, pk_cmul(G00, a0));
    v2f n1 = pk_cmul_acc(G11, a1, pk_cmul(G10, a0));
    v2f n2 = pk_cmul_acc(G01, a3, pk_cmul(G00, a2));
    v2f n3 = pk_cmul_acc(G11, a3, pk_cmul(G10, a2));
    pk_rx(n1, n3, cm2[15]);          // CRX(15,0): ctrl w15 (rg b0), tgt w0 (rg b1)
    float p0 = n0.x*n0.x + n0.y*n0.y;
    float p1 = n1.x*n1.x + n1.y*n1.y;
    float p2 = n2.x*n2.x + n2.y*n2.y;
    float p3 = n3.x*n3.x + n3.y*n3.y;
    float ps = p0+p1+p2+p3;
    tot += ps;
    S15 += p1+p3;
    S0w += p2+p3;
    if (t2&1) S9 += ps;
    if (t2&2) S1w += ps;
  }
  float s = tot;
  float u[6];
  #pragma unroll
  for (int b=0;b<6;b++){
    int m = 1<<b;
    float tt = __shfl_xor(s, m, 64);
    u[b] = s - tt;
    s = s + tt;
    #pragma unroll
    for (int j=0;j<6;j++) if (j<b) u[j] += __shfl_xor(u[j], m, 64);
  }
  #pragma unroll
  for (int d=1; d<64; d<<=1){
    S15 += __shfl_xor(S15, d, 64);
    S0w += __shfl_xor(S0w, d, 64);
    S9  += __shfl_xor(S9, d, 64);
    S1w += __shfl_xor(S1w, d, 64);
  }
  __syncthreads();
  float* ef = (float*)lbufA;
  if (lane==0){
    ef[wv*16+11]=u[0]; ef[wv*16+12]=u[1]; ef[wv*16+13]=u[2]; ef[wv*16+14]=u[3];
    ef[wv*16+7]=u[4];  ef[wv*16+8]=u[5];
    ef[wv*16+15]=s-2.f*S15; ef[wv*16+0]=s-2.f*S0w;
    ef[wv*16+9]=s-2.f*S9;   ef[wv*16+1]=s-2.f*S1w;
    ef[wv*16+10]=(wv&1)?-s:s; ef[wv*16+6]=(wv&2)?-s:s;
    ef[wv*16+2]=(h&1)?-s:s; ef[wv*16+3]=(h&2)?-s:s;
    ef[wv*16+4]=(h&4)?-s:s; ef[wv*16+5]=(h&8)?-s:s;
  }
  __syncthreads();
  if (threadIdx.x < 16){
    float r4 = ef[threadIdx.x]+ef[16+threadIdx.x]+ef[32+threadIdx.x]+ef[48+threadIdx.x];
    atomicAdd(expv + (size_t)bg*NQ + threadIdx.x, r4);
  }
}

__global__ __launch_bounds__(128) void klogits(const float* __restrict__ expv,
      const float* __restrict__ W, const float* __restrict__ bias,
      float* __restrict__ out)
{
  int b = blockIdx.x;
  int tid = threadIdx.x;
  __shared__ float f[NQ];
  __shared__ float lg[NCLS];
  if (tid < NQ) f[tid] = expv[b*NQ + tid];
  __syncthreads();
  if (tid < NCLS){
    float acc = bias[tid];
    #pragma unroll
    for (int i=0;i<NQ;i++) acc += f[i]*W[tid*NQ+i];
    lg[tid] = acc;
  }
  __syncthreads();
  if (tid < NCLS){
    float m = -1e30f;
    for (int i=0;i<NCLS;i++) m = fmaxf(m, lg[i]);
    float sum = 0.f;
    for (int i=0;i<NCLS;i++) sum += expf(lg[i]-m);
    out[b*NCLS+tid] = lg[tid] - m - logf(sum);
  }
}

extern "C" void kernel_launch(void* const* d_in, const int* in_sizes, int n_in,
                              void* d_out, int out_size, void* d_ws, size_t ws_size,
                              hipStream_t stream)
{
  const float* x    = (const float*)d_in[0];
  const float* rot1 = (const float*)d_in[1];
  const float* crx1 = (const float*)d_in[2];
  const float* rot2 = (const float*)d_in[3];
  const float* crx2 = (const float*)d_in[4];
  const float* W    = (const float*)d_in[5];
  const float* bias = (const float*)d_in[6];
  float* out = (float*)d_out;

  char* ws = (char*)d_ws;
  float* expv = (float*)ws;                           // 32 KB  @ 0
  v2f*   fU   = (v2f*)(ws + (40<<10));                // 512 KB @ 40K
  v2f*   cmm  = (v2f*)(ws + (560<<10));               // 256 B  @ 560K
  v2f*   Tbl  = (v2f*)(ws + (564<<10));               // 128 KB @ 564K
  _Float16* Bt16 = (_Float16*)(ws + (704<<10));       // 4 MB   @ 704K  (4096 rows x 1KB)
  f16x2* compact = (f16x2*)(ws + (4800<<10));         // 8 MB   @ 4800K (after Bt16!)
  const size_t stOff = (size_t)(4800<<10) + ((size_t)NBATCH<<14);   // 12992K
  f16x2* st   = (f16x2*)(ws + stOff);

  hipMemsetAsync(expv, 0, NBATCH*NQ*sizeof(float), stream);
  kprep<<<(2*NBATCH*NQ + 255)/256, 256, 0, stream>>>(x, rot1, crx1, rot2, crx2, fU, cmm);

  v2f* fU1 = fU;
  v2f* fU2 = fU + 32768;
  v2f* cm1 = cmm;
  v2f* cm2 = cmm + 16;

  kprep2<<<(2*NBATCH + 255)/256, 256, 0, stream>>>(fU1, cm1, Tbl);
  kprepG<<<(NBATCH*2*2*16 + 255)/256, 256, 0, stream>>>(fU2, cm2, Bt16);
  kpass1<<<NBATCH, 256, 0, stream>>>(fU1, cm1, compact);

  size_t avail = (ws_size > stOff) ? (ws_size - stOff) : 0;
  int chunk = NBATCH;
  while (chunk > 1 && (size_t)chunk*65536*sizeof(f16x2) > avail) chunk >>= 1;

  for (int b0 = 0; b0 < NBATCH; b0 += chunk){
    kpass2<<<chunk*16, 256, 0, stream>>>(compact, Tbl, fU2, cm1, cm2, st, b0);
    kpass3<<<chunk*16, 256, 0, stream>>>(st, fU2, cm2, (const half8*)Bt16, expv, b0);
  }
  klogits<<<NBATCH, 128, 0, stream>>>(expv, W, bias, out);
}